// Round 5
// baseline (886.171 us; speedup 1.0000x reference)
//
#include <hip/hip_runtime.h>
#include <hip/hip_bf16.h>

// Problem constants
#define BN_B 64
#define NC 5
#define NH 50
#define NL 32
#define DD 300
#define QQ 200
#define NVOC 50000
#define NGAT 55          // 5 candidate + 50 clicked news GATs
#define NROW 2048        // rows per news GAT (B*L)
#define NUSR 3200        // rows user GAT (B*H)
#define NUSR_PAD 3328    // 13*256
#define CW 304           // prefix array row width (300 data + col300 = denominator)
#define NT_NEWS 128      // 2048/16
#define NT_USER 208      // 3328/16
#define NB_NEWS 128      // max bucket index = NROW/16
#define NB_USER 200      // max bucket index = NUSR/16
#define GSTR 320         // padded g row stride (10 K-tiles of 32 for MFMA)
#define NTILES_N 13      // ceil(200/16)
#define KTILES 10        // 320/32
#define BPELT (NTILES_N * KTILES * 64)  // B-fragment entries (x8 bf16 each)
// W-GEMM (split bf16 MFMA) tiling: N=304 -> 19 n-tiles, K=320 -> 10 k-tiles
#define WNT 19
#define WKT 10
#define WPELT (WNT * WKT * 64)

typedef short bf16x8 __attribute__((ext_vector_type(8)));
typedef float f32x4 __attribute__((ext_vector_type(4)));

// ---------------------------------------------------------------------------
// Pack W [300,300] fp32 -> split bf16 (hi/lo) B-fragments for 16x16x32 MFMA.
// ---------------------------------------------------------------------------
__global__ __launch_bounds__(256) void k_packW(const float* __restrict__ Wm,
                                               __hip_bfloat16* __restrict__ Bhi,
                                               __hip_bfloat16* __restrict__ Blo) {
  int e = blockIdx.x * 256 + threadIdx.x;
  if (e >= WPELT) return;
  int lane = e & 63, nt = (e >> 6) % WNT, kt = (e >> 6) / WNT;
  int n = nt * 16 + (lane & 15);
  int k0 = kt * 32 + (lane >> 4) * 8;
  __hip_bfloat16 hv[8], lv[8];
#pragma unroll
  for (int j = 0; j < 8; ++j) {
    int k = k0 + j;
    float v = (k < DD && n < DD) ? Wm[(size_t)k * DD + n] : 0.f;
    __hip_bfloat16 h = __float2bfloat16(v);
    hv[j] = h;
    lv[j] = __float2bfloat16(v - __bfloat162float(h));
  }
  *(bf16x8*)(Bhi + (size_t)e * 8) = *(const bf16x8*)hv;
  *(bf16x8*)(Blo + (size_t)e * 8) = *(const bf16x8*)lv;
}

// ---------------------------------------------------------------------------
// C[M,300] = A[M,300] @ W[300,300] via split-bf16 MFMA (3 products ~ fp32).
// ---------------------------------------------------------------------------
__global__ __launch_bounds__(256) void k_gemm_mfma(const float* __restrict__ A,
                                                   const __hip_bfloat16* __restrict__ Bhi,
                                                   const __hip_bfloat16* __restrict__ Blo,
                                                   float* __restrict__ C, int M) {
  const int tid = threadIdx.x;
  const int wave = tid >> 6, lane = tid & 63;
  const int quad = lane >> 4, l16 = lane & 15;
  const int rowA = blockIdx.x * 64 + wave * 16 + l16;
  const float* ar = A + (size_t)rowA * DD;
  f32x4 acc[WNT];
#pragma unroll
  for (int nt = 0; nt < WNT; ++nt) acc[nt] = (f32x4){0.f, 0.f, 0.f, 0.f};

  for (int kt = 0; kt < WKT; ++kt) {
    const int k0 = kt * 32 + quad * 8;
    float av[8];
    if (rowA < M && k0 + 8 <= DD) {
      float4 v0 = *(const float4*)(ar + k0);
      float4 v1 = *(const float4*)(ar + k0 + 4);
      av[0] = v0.x; av[1] = v0.y; av[2] = v0.z; av[3] = v0.w;
      av[4] = v1.x; av[5] = v1.y; av[6] = v1.z; av[7] = v1.w;
    } else {
#pragma unroll
      for (int j = 0; j < 8; ++j) {
        int k = k0 + j;
        av[j] = (rowA < M && k < DD) ? ar[k] : 0.f;
      }
    }
    __hip_bfloat16 hv[8], lv[8];
#pragma unroll
    for (int j = 0; j < 8; ++j) {
      __hip_bfloat16 h = __float2bfloat16(av[j]);
      hv[j] = h;
      lv[j] = __float2bfloat16(av[j] - __bfloat162float(h));
    }
    const bf16x8 ah = *(const bf16x8*)hv;
    const bf16x8 al = *(const bf16x8*)lv;
    const bf16x8* bh = (const bf16x8*)Bhi + (size_t)(kt * WNT) * 64 + lane;
    const bf16x8* bl = (const bf16x8*)Blo + (size_t)(kt * WNT) * 64 + lane;
#pragma unroll
    for (int nt = 0; nt < WNT; ++nt) {
      bf16x8 bhf = bh[nt * 64], blf = bl[nt * 64];
      acc[nt] = __builtin_amdgcn_mfma_f32_16x16x32_bf16(ah, bhf, acc[nt], 0, 0, 0);
      acc[nt] = __builtin_amdgcn_mfma_f32_16x16x32_bf16(al, bhf, acc[nt], 0, 0, 0);
      acc[nt] = __builtin_amdgcn_mfma_f32_16x16x32_bf16(ah, blf, acc[nt], 0, 0, 0);
    }
  }
  const int mbase = blockIdx.x * 64 + wave * 16 + quad * 4;
#pragma unroll
  for (int nt = 0; nt < WNT; ++nt) {
    int n = nt * 16 + l16;
    if (n < DD) {
#pragma unroll
      for (int r = 0; r < 4; ++r) {
        int mr = mbase + r;
        if (mr < M) C[(size_t)mr * DD + n] = acc[nt][r];
      }
    }
  }
}

// ---------------------------------------------------------------------------
// s1/s2 per row
// ---------------------------------------------------------------------------
__global__ __launch_bounds__(256) void k_sv(const float* __restrict__ Wh,
                                            const float* __restrict__ avec,
                                            float* __restrict__ s1, float* __restrict__ s2, int M) {
  int row = blockIdx.x * 4 + (threadIdx.x >> 6);
  int lane = threadIdx.x & 63;
  if (row >= M) return;
  const float* wr = Wh + (size_t)row * DD;
  float p1 = 0.f, p2 = 0.f;
  for (int d = lane; d < DD; d += 64) {
    float w = wr[d];
    p1 = fmaf(w, avec[d], p1);
    p2 = fmaf(w, avec[DD + d], p2);
  }
  for (int o = 32; o; o >>= 1) { p1 += __shfl_xor(p1, o, 64); p2 += __shfl_xor(p2, o, 64); }
  if (lane == 0) { s1[row] = p1; s2[row] = p2; }
}

// ---------------------------------------------------------------------------
// Bitonic sort of s2 + exp tables + rank/bucket epilogue.
// Outputs: perm/E1/E02 (sorted order), rlist[(ki<<16)|r] bucket-ordered,
// rs1 (s1 per bucket slot), boff (bucket offsets, NB+2 per GAT).
// ---------------------------------------------------------------------------
__global__ __launch_bounds__(1024) void k_sort2(const int* __restrict__ cand,
                                                const int* __restrict__ clicked,
                                                const float* __restrict__ s2src,
                                                const float* __restrict__ s1src,
                                                int* __restrict__ perm,
                                                float* __restrict__ E1, float* __restrict__ E02,
                                                int* __restrict__ rlist, float* __restrict__ rs1,
                                                int* __restrict__ boff,
                                                int mode, int N, int SZ, int Epad, int NB) {
  __shared__ float sval[4096];
  __shared__ int spay[4096];
  __shared__ int cnt[224];
  __shared__ int ofs[224];
  const int m = blockIdx.x;
  const int tid = threadIdx.x;
  int* perm_g = perm + (size_t)m * Epad;
  float* E1_g = E1 + (size_t)m * Epad;
  float* E02_g = E02 + (size_t)m * Epad;

  for (int i = tid; i < SZ; i += 1024) {
    float v; int p;
    if (mode == 0) {
      int b = i >> 5, l = i & 31;
      int tok = (m < NC) ? cand[b * (NC * NL) + m * NL + l]
                         : clicked[b * (NH * NL) + (m - NC) * NL + l];
      v = s2src[tok]; p = tok;
    } else {
      if (i < N) { v = s2src[i]; p = i; } else { v = __builtin_inff(); p = 0; }
    }
    sval[i] = v; spay[i] = p;
  }
  __syncthreads();
  for (int k = 2; k <= SZ; k <<= 1) {
    for (int j = k >> 1; j > 0; j >>= 1) {
      for (int i = tid; i < SZ; i += 1024) {
        int ixj = i ^ j;
        if (ixj > i) {
          bool asc = ((i & k) == 0);
          float a = sval[i], bb = sval[ixj];
          bool sw = asc ? (a > bb) : (a < bb);
          if (sw) {
            sval[i] = bb; sval[ixj] = a;
            int t = spay[i]; spay[i] = spay[ixj]; spay[ixj] = t;
          }
        }
      }
      __syncthreads();
    }
  }
  for (int i = tid; i < Epad; i += 1024) {
    E1_g[i] = (i < N) ? expf(sval[i]) : 0.f;
    E02_g[i] = (i < N) ? expf(0.2f * sval[i]) : 0.f;
    perm_g[i] = spay[i];
  }
  __syncthreads();
  // ---- rank + bucket epilogue (sval = sorted s2 still in LDS) ----
  for (int t = tid; t <= NB; t += 1024) cnt[t] = 0;
  __syncthreads();
  int* kil = spay;  // reuse (perm already written)
  for (int r = tid; r < N; r += 1024) {
    int tok;
    if (mode == 0) {
      int b = r >> 5, l = r & 31;
      tok = (m < NC) ? cand[b * (NC * NL) + m * NL + l]
                     : clicked[b * (NH * NL) + (m - NC) * NL + l];
    } else tok = r;
    float tau = -s1src[tok];
    int lo = 0, hi = N;
    while (lo < hi) { int mid = (lo + hi) >> 1; if (sval[mid] <= tau) lo = mid + 1; else hi = mid; }
    kil[r] = lo;
    atomicAdd(&cnt[lo >> 4], 1);
  }
  __syncthreads();
  if (tid == 0) {
    int run = 0;
    for (int t = 0; t <= NB; ++t) { ofs[t] = run; run += cnt[t]; cnt[t] = ofs[t]; }
  }
  __syncthreads();
  int* rlist_g = rlist + (size_t)m * N;
  float* rs1_g = rs1 + (size_t)m * N;
  for (int r = tid; r < N; r += 1024) {
    int ki = kil[r];
    int pos = atomicAdd(&cnt[ki >> 4], 1);
    rlist_g[pos] = (ki << 16) | r;
    int tok;
    if (mode == 0) {
      int b = r >> 5, l = r & 31;
      tok = (m < NC) ? cand[b * (NC * NL) + m * NL + l]
                     : clicked[b * (NH * NL) + (m - NC) * NL + l];
    } else tok = r;
    rs1_g[pos] = s1src[tok];
  }
  int* boff_g = boff + (size_t)m * (NB + 2);
  for (int t = tid; t <= NB; t += 1024) boff_g[t] = ofs[t];
  if (tid == 0) boff_g[NB + 1] = N;
}

// ---------------------------------------------------------------------------
// Chunked weighted prefix accumulation at granularity 16 (local prefixes)
// + per-256-chunk totals T (for parallel fix-up).
// ---------------------------------------------------------------------------
__global__ __launch_bounds__(320) void k_scan(const float* __restrict__ base,
                                              const int* __restrict__ perm,
                                              const float* __restrict__ E1,
                                              const float* __restrict__ E02,
                                              float* __restrict__ C1, float* __restrict__ C02,
                                              float* __restrict__ T1, float* __restrict__ T02,
                                              int Epad, int cstride, int nkc) {
  const int g = blockIdx.y, kc = blockIdx.x;
  const int col = threadIdx.x;
  const int* perm_g = perm + (size_t)g * Epad;
  const float* E1_g = E1 + (size_t)g * Epad;
  const float* E02_g = E02 + (size_t)g * Epad;
  float* C1_g = C1 + (size_t)g * cstride * CW;
  float* C02_g = C02 + (size_t)g * cstride * CW;
  const bool datacol = (col < DD);
  const float wden = (col == DD) ? 1.f : 0.f;
  float acc1 = 0.f, acc2 = 0.f;
  const int k0 = kc * 256;
#pragma unroll 8
  for (int kk = 0; kk < 256; ++kk) {
    int k = k0 + kk;
    int tok = perm_g[k];
    float e1 = E1_g[k], e02 = E02_g[k];
    float w = datacol ? base[(size_t)tok * DD + col] : wden;
    acc1 = fmaf(e1, w, acc1);
    acc2 = fmaf(e02, w, acc2);
    if ((kk & 15) == 15) {
      int t = (k + 1) >> 4;
      if (col < CW) { C1_g[(size_t)t * CW + col] = acc1; C02_g[(size_t)t * CW + col] = acc2; }
    }
  }
  if (col < CW) {
    T1[((size_t)g * nkc + kc) * CW + col] = acc1;
    T02[((size_t)g * nkc + kc) * CW + col] = acc2;
  }
}

// Parallel fix-up: add sum of previous chunk totals to local prefixes; row0=0.
__global__ __launch_bounds__(320) void k_fix2(float* __restrict__ C1, float* __restrict__ C02,
                                              const float* __restrict__ T1,
                                              const float* __restrict__ T02,
                                              int nkc, int cstride) {
  const int kc = blockIdx.x, g = blockIdx.y, col = threadIdx.x;
  if (col >= CW) return;
  float* C1_g = C1 + (size_t)g * cstride * CW;
  float* C02_g = C02 + (size_t)g * cstride * CW;
  if (kc == 0) { C1_g[col] = 0.f; C02_g[col] = 0.f; return; }
  float off1 = 0.f, off2 = 0.f;
  for (int c = 0; c < kc; ++c) {
    off1 += T1[((size_t)g * nkc + c) * CW + col];
    off2 += T02[((size_t)g * nkc + c) * CW + col];
  }
  for (int tl = 1; tl <= 16; ++tl) {
    size_t idx = (size_t)(kc * 16 + tl) * CW + col;
    C1_g[idx] += off1;
    C02_g[idx] += off2;
  }
}

// ---------------------------------------------------------------------------
// Bucketed GAT row construction: block = (chunk t, gat g). Builds 16 level
// vectors U1/U02 in LDS (chunk EW rows read ONCE per block), then emits all
// rows of the bucket as LDS reads + 2 FMA/element. Writes bf16, stride GSTR.
// ---------------------------------------------------------------------------
__global__ __launch_bounds__(320) void k_rows2(
    const float* __restrict__ base,
    const int* __restrict__ perm, const float* __restrict__ E1, const float* __restrict__ E02,
    const float* __restrict__ C1, const float* __restrict__ C02,
    const int* __restrict__ rlist, const float* __restrict__ rs1,
    const int* __restrict__ boff,
    __hip_bfloat16* __restrict__ gout,
    int N, int NT, int Epad, int NB) {
  __shared__ float U1[16][CW];
  __shared__ float U02[16][CW];
  const int t = blockIdx.x, g = blockIdx.y;
  const int col = threadIdx.x;  // 0..319 (== GSTR)
  const int* boff_g = boff + (size_t)g * (NB + 2);
  const int i0 = boff_g[t], i1 = boff_g[t + 1];
  const float* C1_g = C1 + (size_t)g * (NT + 1) * CW;
  const float* C02_g = C02 + (size_t)g * (NT + 1) * CW;
  const int* perm_g = perm + (size_t)g * Epad;
  const float* E1_g = E1 + (size_t)g * Epad;
  const float* E02_g = E02 + (size_t)g * Epad;

  float u1 = 0.f, u02 = 0.f;
  if (col < CW) {
    u1 = C1_g[(size_t)NT * CW + col] - C1_g[(size_t)t * CW + col];
    u02 = C02_g[(size_t)t * CW + col];
  }
#pragma unroll 4
  for (int j = 0; j < 16; ++j) {
    if (col < CW) { U1[j][col] = u1; U02[j][col] = u02; }
    int idx = t * 16 + j;
    if (idx < N) {
      int tok = perm_g[idx];
      float e1 = E1_g[idx], e02 = E02_g[idx];
      float w;
      if (col < DD) w = base[(size_t)tok * DD + col];
      else w = (col == DD) ? 1.f : 0.f;
      u1 = fmaf(-e1, w, u1);
      u02 = fmaf(e02, w, u02);
    }
  }
  __syncthreads();
  const int* rlist_g = rlist + (size_t)g * N;
  const float* rs1_g = rs1 + (size_t)g * N;
  for (int i = i0; i < i1; ++i) {
    int e = rlist_g[i];
    int r = e & 0xffff, nr = (e >> 16) & 15;
    float s1 = rs1_g[i];
    float es1 = expf(s1), es02 = expf(0.2f * s1);
    float den = es1 * U1[nr][DD] + es02 * U02[nr][DD];
    float rden = 1.f / den;
    float ev = 0.f;
    if (col < DD) {
      float num = es1 * U1[nr][col] + es02 * U02[nr][col];
      float gg = num * rden;
      ev = (gg > 0.f) ? gg : expm1f(gg);
    }
    gout[((size_t)g * N + r) * GSTR + col] = __float2bfloat16(ev);
  }
}

// ---------------------------------------------------------------------------
// Pack lin_w [Q,300] fp32 -> bf16 B-fragments for mfma_f32_16x16x32_bf16.
// ---------------------------------------------------------------------------
__global__ __launch_bounds__(256) void k_packB(const float* __restrict__ lw,
                                               __hip_bfloat16* __restrict__ Bp) {
  int e = blockIdx.x * 256 + threadIdx.x;
  if (e >= BPELT) return;
  int lane = e & 63, kt = (e >> 6) % KTILES, nt = (e >> 6) / KTILES;
  int n = nt * 16 + (lane & 15);
  int k0 = kt * 32 + (lane >> 4) * 8;
  __hip_bfloat16 vals[8];
#pragma unroll
  for (int j = 0; j < 8; ++j) {
    int k = k0 + j;
    float v = (n < QQ && k < DD) ? lw[(size_t)n * DD + k] : 0.f;
    vals[j] = __float2bfloat16(v);
  }
  *(bf16x8*)(Bp + (size_t)e * 8) = *(const bf16x8*)vals;
}

// ---------------------------------------------------------------------------
// logits[r] = tanh(g[r,:] @ lin_w.T + b) . query  via bf16 MFMA.
// ---------------------------------------------------------------------------
__global__ __launch_bounds__(256) void k_logits(
    const __hip_bfloat16* __restrict__ g, const __hip_bfloat16* __restrict__ Bp,
    const float* __restrict__ lin_b, const float* __restrict__ query,
    float* __restrict__ logits) {
  const int tid = threadIdx.x;
  const int wave = tid >> 6, lane = tid & 63;
  const int quad = lane >> 4, l16 = lane & 15;
  const int rbase = blockIdx.x * 64 + wave * 16;
  const __hip_bfloat16* grow = g + (size_t)(rbase + l16) * GSTR + quad * 8;
  bf16x8 afr[KTILES];
#pragma unroll
  for (int kt = 0; kt < KTILES; ++kt)
    afr[kt] = *(const bf16x8*)(grow + kt * 32);
  float part[4] = {0.f, 0.f, 0.f, 0.f};
  for (int nt = 0; nt < NTILES_N; ++nt) {
    f32x4 acc = {0.f, 0.f, 0.f, 0.f};
    const bf16x8* bp = (const bf16x8*)Bp + (size_t)nt * KTILES * 64 + lane;
#pragma unroll
    for (int kt = 0; kt < KTILES; ++kt)
      acc = __builtin_amdgcn_mfma_f32_16x16x32_bf16(afr[kt], bp[kt * 64], acc, 0, 0, 0);
    const int n = nt * 16 + l16;
    const float qv = (n < QQ) ? query[n] : 0.f;
    const float bv = (n < QQ) ? lin_b[n] : 0.f;
#pragma unroll
    for (int r = 0; r < 4; ++r)
      part[r] = fmaf(tanhf(acc[r] + bv), qv, part[r]);
  }
#pragma unroll
  for (int r = 0; r < 4; ++r) {
    float p = part[r];
    p += __shfl_xor(p, 1, 64); p += __shfl_xor(p, 2, 64);
    p += __shfl_xor(p, 4, 64); p += __shfl_xor(p, 8, 64);
    if (l16 == 0) logits[rbase + quad * 4 + r] = p;
  }
}

// ---------------------------------------------------------------------------
// News additive attention: softmax over 32 logits + weighted sum of g rows.
// ---------------------------------------------------------------------------
__global__ __launch_bounds__(192) void k_attn_lite(
    const __hip_bfloat16* __restrict__ g, const float* __restrict__ logits,
    float* __restrict__ cand_enc, float* __restrict__ clicked_enc) {
  __shared__ float wgt[32];
  const int b = blockIdx.x, m = blockIdx.y, tid = threadIdx.x;
  if (tid < 32) {
    float lg = logits[(size_t)m * NROW + b * NL + tid];
    float mx = lg;
    for (int o = 16; o; o >>= 1) mx = fmaxf(mx, __shfl_xor(mx, o, 32));
    float e = expf(lg - mx);
    float sm = e;
    for (int o = 16; o; o >>= 1) sm += __shfl_xor(sm, o, 32);
    wgt[tid] = e / sm;
  }
  __syncthreads();
  if (tid < 150) {
    const __hip_bfloat16* base = g + (size_t)(m * NROW + b * NL) * GSTR;
    float a0 = 0.f, a1 = 0.f;
#pragma unroll 8
    for (int l = 0; l < 32; ++l) {
      unsigned u = *(const unsigned*)(base + (size_t)l * GSTR + 2 * tid);
      float w = wgt[l];
      a0 = fmaf(w, __uint_as_float(u << 16), a0);
      a1 = fmaf(w, __uint_as_float(u & 0xffff0000u), a1);
    }
    float* outp = (m < NC) ? (cand_enc + ((size_t)b * NC + m) * DD)
                           : (clicked_enc + ((size_t)b * NH + (m - NC)) * DD);
    outp[2 * tid] = a0; outp[2 * tid + 1] = a1;
  }
}

// User additive attention: softmax over 50 logits + weighted sum.
__global__ __launch_bounds__(192) void k_attn_user_lite(
    const __hip_bfloat16* __restrict__ g, const float* __restrict__ logits,
    float* __restrict__ user_enc) {
  __shared__ float wgt[64];
  const int b = blockIdx.x, tid = threadIdx.x;
  if (tid < 64) {
    float lg = (tid < NH) ? logits[(size_t)b * NH + tid] : -__builtin_inff();
    float mx = lg;
    for (int o = 32; o; o >>= 1) mx = fmaxf(mx, __shfl_xor(mx, o, 64));
    float e = (tid < NH) ? expf(lg - mx) : 0.f;
    float sm = e;
    for (int o = 32; o; o >>= 1) sm += __shfl_xor(sm, o, 64);
    wgt[tid] = e / sm;
  }
  __syncthreads();
  if (tid < 150) {
    const __hip_bfloat16* base = g + (size_t)(b * NH) * GSTR;
    float a0 = 0.f, a1 = 0.f;
#pragma unroll 10
    for (int h = 0; h < NH; ++h) {
      unsigned u = *(const unsigned*)(base + (size_t)h * GSTR + 2 * tid);
      float w = wgt[h];
      a0 = fmaf(w, __uint_as_float(u << 16), a0);
      a1 = fmaf(w, __uint_as_float(u & 0xffff0000u), a1);
    }
    user_enc[(size_t)b * DD + 2 * tid] = a0;
    user_enc[(size_t)b * DD + 2 * tid + 1] = a1;
  }
}

// Final: out[b,c] = cand_enc[b,c,:]·user_enc[b,:]
__global__ __launch_bounds__(64) void k_dot(const float* __restrict__ cand_enc,
                                            const float* __restrict__ user_enc,
                                            float* __restrict__ out) {
  const int bc = blockIdx.x, b = bc / NC, lane = threadIdx.x;
  const float* cp = cand_enc + (size_t)bc * DD;
  const float* up = user_enc + (size_t)b * DD;
  float s = 0.f;
  for (int d = lane; d < DD; d += 64) s = fmaf(cp[d], up[d], s);
  for (int o = 32; o; o >>= 1) s += __shfl_xor(s, o, 64);
  if (lane == 0) out[bc] = s;
}

// ---------------------------------------------------------------------------
extern "C" void kernel_launch(void* const* d_in, const int* in_sizes, int n_in,
                              void* d_out, int out_size, void* d_ws, size_t ws_size,
                              hipStream_t stream) {
  const int* cand = (const int*)d_in[0];
  const int* clicked = (const int*)d_in[1];
  const float* emb = (const float*)d_in[2];
  const float* news_W = (const float*)d_in[3];
  const float* news_a = (const float*)d_in[4];
  const float* news_lw = (const float*)d_in[5];
  const float* news_lb = (const float*)d_in[6];
  const float* news_q = (const float*)d_in[7];
  const float* user_W = (const float*)d_in[8];
  const float* user_a = (const float*)d_in[9];
  const float* user_lw = (const float*)d_in[10];
  const float* user_lb = (const float*)d_in[11];
  const float* user_q = (const float*)d_in[12];
  float* out = (float*)d_out;

  float* W = (float*)d_ws;
  size_t o = 0;
  auto nxt = [&](size_t n) { size_t c = o; o += (n + 63) & ~(size_t)63; return c; };
  float* EW = W + nxt((size_t)NVOC * DD);
  float* s1v = W + nxt(NVOC);
  float* s2v = W + nxt(NVOC);
  int* perm = (int*)(W + nxt((size_t)NGAT * NROW));
  float* E1 = W + nxt((size_t)NGAT * NROW);
  float* E02 = W + nxt((size_t)NGAT * NROW);
  float* C1 = W + nxt((size_t)NGAT * (NT_NEWS + 1) * CW);
  float* C02 = W + nxt((size_t)NGAT * (NT_NEWS + 1) * CW);
  float* T1N = W + nxt((size_t)NGAT * 8 * CW);
  float* T02N = W + nxt((size_t)NGAT * 8 * CW);
  int* rlistN = (int*)(W + nxt((size_t)NGAT * NROW));
  float* rs1N = W + nxt((size_t)NGAT * NROW);
  int* boffN = (int*)(W + nxt((size_t)NGAT * (NB_NEWS + 2)));
  float* cand_enc = W + nxt((size_t)BN_B * NC * DD);
  float* clicked_enc = W + nxt((size_t)BN_B * NH * DD);
  float* WhU = W + nxt((size_t)NUSR * DD);
  float* s1u = W + nxt(NUSR);
  float* s2u = W + nxt(NUSR);
  int* permU = (int*)(W + nxt(NUSR_PAD));
  float* E1U = W + nxt(NUSR_PAD);
  float* E02U = W + nxt(NUSR_PAD);
  float* C1U = W + nxt((size_t)(NT_USER + 1) * CW);
  float* C02U = W + nxt((size_t)(NT_USER + 1) * CW);
  float* T1U = W + nxt((size_t)13 * CW);
  float* T02U = W + nxt((size_t)13 * CW);
  int* rlistU = (int*)(W + nxt(NUSR));
  float* rs1U = W + nxt(NUSR);
  int* boffU = (int*)(W + nxt(NB_USER + 2));
  float* user_enc = W + nxt((size_t)BN_B * DD);
  float* logitsN = W + nxt((size_t)NGAT * NROW);
  float* logitsU = W + nxt(NUSR);
  __hip_bfloat16* BpN = (__hip_bfloat16*)(W + nxt((size_t)BPELT * 8 / 2));
  __hip_bfloat16* BpU = (__hip_bfloat16*)(W + nxt((size_t)BPELT * 8 / 2));
  __hip_bfloat16* WhiN = (__hip_bfloat16*)(W + nxt((size_t)WPELT * 8 / 2));
  __hip_bfloat16* WloN = (__hip_bfloat16*)(W + nxt((size_t)WPELT * 8 / 2));
  __hip_bfloat16* WhiU = (__hip_bfloat16*)(W + nxt((size_t)WPELT * 8 / 2));
  __hip_bfloat16* WloU = (__hip_bfloat16*)(W + nxt((size_t)WPELT * 8 / 2));
  __hip_bfloat16* g_news = (__hip_bfloat16*)(W + nxt((size_t)NGAT * NROW * GSTR / 2));
  __hip_bfloat16* g_user = (__hip_bfloat16*)(W + nxt((size_t)NUSR * GSTR / 2));

  const int packgrid = (BPELT + 255) / 256;
  const int packWgrid = (WPELT + 255) / 256;

  // 1. EW = emb @ news_W  (split-bf16 MFMA, ~fp32 accuracy)
  k_packW<<<packWgrid, 256, 0, stream>>>(news_W, WhiN, WloN);
  k_gemm_mfma<<<(NVOC + 63) / 64, 256, 0, stream>>>(emb, WhiN, WloN, EW, NVOC);
  // 2. per-vocab attention scalars
  k_sv<<<(NVOC + 3) / 4, 256, 0, stream>>>(EW, news_a, s1v, s2v, NVOC);
  // 3. sort + exp tables + rank/bucket per news GAT
  k_sort2<<<NGAT, 1024, 0, stream>>>(cand, clicked, s2v, s1v, perm, E1, E02,
                                     rlistN, rs1N, boffN, 0, NROW, NROW, NROW, NB_NEWS);
  // 4-5. coarse weighted prefix sums + parallel fix-up
  k_scan<<<dim3(8, NGAT), 320, 0, stream>>>(EW, perm, E1, E02, C1, C02, T1N, T02N,
                                            NROW, NT_NEWS + 1, 8);
  k_fix2<<<dim3(8, NGAT), 320, 0, stream>>>(C1, C02, T1N, T02N, 8, NT_NEWS + 1);
  // 6. bucketed GAT rows -> g_news
  k_rows2<<<dim3(NB_NEWS + 1, NGAT), 320, 0, stream>>>(EW, perm, E1, E02, C1, C02,
                                                       rlistN, rs1N, boffN, g_news,
                                                       NROW, NT_NEWS, NROW, NB_NEWS);
  // 7. MFMA logits + lite attention -> cand/clicked encodings
  k_packB<<<packgrid, 256, 0, stream>>>(news_lw, BpN);
  k_logits<<<NGAT * NROW / 64, 256, 0, stream>>>(g_news, BpN, news_lb, news_q, logitsN);
  k_attn_lite<<<dim3(BN_B, NGAT), 192, 0, stream>>>(g_news, logitsN, cand_enc, clicked_enc);
  // 8-12. user GAT over clicked encodings
  k_packW<<<packWgrid, 256, 0, stream>>>(user_W, WhiU, WloU);
  k_gemm_mfma<<<(NUSR + 63) / 64, 256, 0, stream>>>(clicked_enc, WhiU, WloU, WhU, NUSR);
  k_sv<<<NUSR / 4, 256, 0, stream>>>(WhU, user_a, s1u, s2u, NUSR);
  k_sort2<<<1, 1024, 0, stream>>>(nullptr, nullptr, s2u, s1u, permU, E1U, E02U,
                                  rlistU, rs1U, boffU, 1, NUSR, 4096, NUSR_PAD, NB_USER);
  k_scan<<<dim3(13, 1), 320, 0, stream>>>(WhU, permU, E1U, E02U, C1U, C02U, T1U, T02U,
                                          NUSR_PAD, NT_USER + 1, 13);
  k_fix2<<<dim3(13, 1), 320, 0, stream>>>(C1U, C02U, T1U, T02U, 13, NT_USER + 1);
  k_rows2<<<dim3(NB_USER + 1, 1), 320, 0, stream>>>(WhU, permU, E1U, E02U, C1U, C02U,
                                                    rlistU, rs1U, boffU, g_user,
                                                    NUSR, NT_USER, NUSR_PAD, NB_USER);
  // 13. user logits + attention
  k_packB<<<packgrid, 256, 0, stream>>>(user_lw, BpU);
  k_logits<<<NUSR / 64, 256, 0, stream>>>(g_user, BpU, user_lb, user_q, logitsU);
  k_attn_user_lite<<<BN_B, 192, 0, stream>>>(g_user, logitsU, user_enc);
  // 14. click score
  k_dot<<<BN_B * NC, 64, 0, stream>>>(cand_enc, user_enc, out);
}

// Round 6
// 787.708 us; speedup vs baseline: 1.1250x; 1.1250x over previous
//
#include <hip/hip_runtime.h>
#include <hip/hip_bf16.h>

// Problem constants
#define BN_B 64
#define NC 5
#define NH 50
#define NL 32
#define DD 300
#define QQ 200
#define NVOC 50000
#define NGAT 55          // 5 candidate + 50 clicked news GATs
#define NROW 2048        // rows per news GAT (B*L)
#define NUSR 3200        // rows user GAT (B*H)
#define NUSR_PAD 3328    // 13*256
#define CW 304           // prefix array row width (300 data + col300 = denominator)
#define NT_NEWS 128      // 2048/16
#define NT_USER 208      // 3328/16
#define NB_NEWS 128      // max bucket index = NROW/16
#define NB_USER 200      // max bucket index = NUSR/16
#define GSTR 320         // padded g row stride (10 K-tiles of 32 for MFMA)
#define NTILES_N 13      // ceil(200/16)
#define KTILES 10        // 320/32
#define BPELT (NTILES_N * KTILES * 64)  // B-fragment entries (x8 bf16 each)
#define WNT 19
#define WKT 10
#define WPELT (WNT * WKT * 64)

typedef short bf16x8 __attribute__((ext_vector_type(8)));
typedef short bf16x4 __attribute__((ext_vector_type(4)));
typedef float f32x4 __attribute__((ext_vector_type(4)));

static __device__ __forceinline__ float bf2f(short s) {
  return __uint_as_float(((unsigned)(unsigned short)s) << 16);
}

// ---------------------------------------------------------------------------
// Pack W [300,300] fp32 -> split bf16 (hi/lo) B-fragments. y = 0 news, 1 user.
// ---------------------------------------------------------------------------
__global__ __launch_bounds__(256) void k_packW(const float* __restrict__ W0,
                                               const float* __restrict__ W1,
                                               __hip_bfloat16* __restrict__ h0,
                                               __hip_bfloat16* __restrict__ l0,
                                               __hip_bfloat16* __restrict__ h1,
                                               __hip_bfloat16* __restrict__ l1) {
  const float* Wm = blockIdx.y ? W1 : W0;
  __hip_bfloat16* Bhi = blockIdx.y ? h1 : h0;
  __hip_bfloat16* Blo = blockIdx.y ? l1 : l0;
  int e = blockIdx.x * 256 + threadIdx.x;
  if (e >= WPELT) return;
  int lane = e & 63, nt = (e >> 6) % WNT, kt = (e >> 6) / WNT;
  int n = nt * 16 + (lane & 15);
  int k0 = kt * 32 + (lane >> 4) * 8;
  __hip_bfloat16 hv[8], lv[8];
#pragma unroll
  for (int j = 0; j < 8; ++j) {
    int k = k0 + j;
    float v = (k < DD && n < DD) ? Wm[(size_t)k * DD + n] : 0.f;
    __hip_bfloat16 h = __float2bfloat16(v);
    hv[j] = h;
    lv[j] = __float2bfloat16(v - __bfloat162float(h));
  }
  *(bf16x8*)(Bhi + (size_t)e * 8) = *(const bf16x8*)hv;
  *(bf16x8*)(Blo + (size_t)e * 8) = *(const bf16x8*)lv;
}

// Pack lin_w [Q,300] -> bf16 B-fragments. y = 0 news, 1 user.
__global__ __launch_bounds__(256) void k_packB(const float* __restrict__ lw0,
                                               const float* __restrict__ lw1,
                                               __hip_bfloat16* __restrict__ B0,
                                               __hip_bfloat16* __restrict__ B1) {
  const float* lw = blockIdx.y ? lw1 : lw0;
  __hip_bfloat16* Bp = blockIdx.y ? B1 : B0;
  int e = blockIdx.x * 256 + threadIdx.x;
  if (e >= BPELT) return;
  int lane = e & 63, kt = (e >> 6) % KTILES, nt = (e >> 6) / KTILES;
  int n = nt * 16 + (lane & 15);
  int k0 = kt * 32 + (lane >> 4) * 8;
  __hip_bfloat16 vals[8];
#pragma unroll
  for (int j = 0; j < 8; ++j) {
    int k = k0 + j;
    float v = (n < QQ && k < DD) ? lw[(size_t)n * DD + k] : 0.f;
    vals[j] = __float2bfloat16(v);
  }
  *(bf16x8*)(Bp + (size_t)e * 8) = *(const bf16x8*)vals;
}

// ---------------------------------------------------------------------------
// C[M,300] = A[M,300] @ W[300,300] via split-bf16 MFMA (3 products ~ fp32),
// fused epilogue: s1[row]=C·avec[0:300], s2[row]=C·avec[300:600].
// ---------------------------------------------------------------------------
__global__ __launch_bounds__(256) void k_gemm_mfma(const float* __restrict__ A,
                                                   const __hip_bfloat16* __restrict__ Bhi,
                                                   const __hip_bfloat16* __restrict__ Blo,
                                                   const float* __restrict__ avec,
                                                   float* __restrict__ C,
                                                   float* __restrict__ s1o,
                                                   float* __restrict__ s2o, int M) {
  const int tid = threadIdx.x;
  const int wave = tid >> 6, lane = tid & 63;
  const int quad = lane >> 4, l16 = lane & 15;
  const int rowA = blockIdx.x * 64 + wave * 16 + l16;
  const float* ar = A + (size_t)rowA * DD;
  f32x4 acc[WNT];
#pragma unroll
  for (int nt = 0; nt < WNT; ++nt) acc[nt] = (f32x4){0.f, 0.f, 0.f, 0.f};

  for (int kt = 0; kt < WKT; ++kt) {
    const int k0 = kt * 32 + quad * 8;
    float av[8];
    if (rowA < M && k0 + 8 <= DD) {
      float4 v0 = *(const float4*)(ar + k0);
      float4 v1 = *(const float4*)(ar + k0 + 4);
      av[0] = v0.x; av[1] = v0.y; av[2] = v0.z; av[3] = v0.w;
      av[4] = v1.x; av[5] = v1.y; av[6] = v1.z; av[7] = v1.w;
    } else {
#pragma unroll
      for (int j = 0; j < 8; ++j) {
        int k = k0 + j;
        av[j] = (rowA < M && k < DD) ? ar[k] : 0.f;
      }
    }
    __hip_bfloat16 hv[8], lv[8];
#pragma unroll
    for (int j = 0; j < 8; ++j) {
      __hip_bfloat16 h = __float2bfloat16(av[j]);
      hv[j] = h;
      lv[j] = __float2bfloat16(av[j] - __bfloat162float(h));
    }
    const bf16x8 ah = *(const bf16x8*)hv;
    const bf16x8 al = *(const bf16x8*)lv;
    const bf16x8* bh = (const bf16x8*)Bhi + (size_t)(kt * WNT) * 64 + lane;
    const bf16x8* bl = (const bf16x8*)Blo + (size_t)(kt * WNT) * 64 + lane;
#pragma unroll
    for (int nt = 0; nt < WNT; ++nt) {
      bf16x8 bhf = bh[nt * 64], blf = bl[nt * 64];
      acc[nt] = __builtin_amdgcn_mfma_f32_16x16x32_bf16(ah, bhf, acc[nt], 0, 0, 0);
      acc[nt] = __builtin_amdgcn_mfma_f32_16x16x32_bf16(al, bhf, acc[nt], 0, 0, 0);
      acc[nt] = __builtin_amdgcn_mfma_f32_16x16x32_bf16(ah, blf, acc[nt], 0, 0, 0);
    }
  }
  const int mbase = blockIdx.x * 64 + wave * 16 + quad * 4;
#pragma unroll
  for (int nt = 0; nt < WNT; ++nt) {
    int n = nt * 16 + l16;
    if (n < DD) {
#pragma unroll
      for (int r = 0; r < 4; ++r) {
        int mr = mbase + r;
        if (mr < M) C[(size_t)mr * DD + n] = acc[nt][r];
      }
    }
  }
  // s1/s2 epilogue
  float a1v[WNT], a2v[WNT];
#pragma unroll
  for (int nt = 0; nt < WNT; ++nt) {
    int n = nt * 16 + l16;
    a1v[nt] = (n < DD) ? avec[n] : 0.f;
    a2v[nt] = (n < DD) ? avec[DD + n] : 0.f;
  }
#pragma unroll
  for (int r = 0; r < 4; ++r) {
    float p1 = 0.f, p2 = 0.f;
#pragma unroll
    for (int nt = 0; nt < WNT; ++nt) {
      p1 = fmaf(acc[nt][r], a1v[nt], p1);
      p2 = fmaf(acc[nt][r], a2v[nt], p2);
    }
    p1 += __shfl_xor(p1, 1, 64); p1 += __shfl_xor(p1, 2, 64);
    p1 += __shfl_xor(p1, 4, 64); p1 += __shfl_xor(p1, 8, 64);
    p2 += __shfl_xor(p2, 1, 64); p2 += __shfl_xor(p2, 2, 64);
    p2 += __shfl_xor(p2, 4, 64); p2 += __shfl_xor(p2, 8, 64);
    int mr = mbase + r;
    if (l16 == 0 && mr < M) { s1o[mr] = p1; s2o[mr] = p2; }
  }
}

// ---------------------------------------------------------------------------
// Bitonic sort of s2 + exp tables + rank/bucket epilogue.
// ---------------------------------------------------------------------------
__global__ __launch_bounds__(1024) void k_sort2(const int* __restrict__ cand,
                                                const int* __restrict__ clicked,
                                                const float* __restrict__ s2src,
                                                const float* __restrict__ s1src,
                                                int* __restrict__ perm,
                                                float* __restrict__ E1, float* __restrict__ E02,
                                                int* __restrict__ rlist, float* __restrict__ rs1,
                                                int* __restrict__ boff,
                                                int mode, int N, int SZ, int Epad, int NB) {
  __shared__ float sval[4096];
  __shared__ int spay[4096];
  __shared__ int cnt[224];
  __shared__ int ofs[224];
  const int m = blockIdx.x;
  const int tid = threadIdx.x;
  int* perm_g = perm + (size_t)m * Epad;
  float* E1_g = E1 + (size_t)m * Epad;
  float* E02_g = E02 + (size_t)m * Epad;

  for (int i = tid; i < SZ; i += 1024) {
    float v; int p;
    if (mode == 0) {
      int b = i >> 5, l = i & 31;
      int tok = (m < NC) ? cand[b * (NC * NL) + m * NL + l]
                         : clicked[b * (NH * NL) + (m - NC) * NL + l];
      v = s2src[tok]; p = tok;
    } else {
      if (i < N) { v = s2src[i]; p = i; } else { v = __builtin_inff(); p = 0; }
    }
    sval[i] = v; spay[i] = p;
  }
  __syncthreads();
  for (int k = 2; k <= SZ; k <<= 1) {
    for (int j = k >> 1; j > 0; j >>= 1) {
      for (int i = tid; i < SZ; i += 1024) {
        int ixj = i ^ j;
        if (ixj > i) {
          bool asc = ((i & k) == 0);
          float a = sval[i], bb = sval[ixj];
          bool sw = asc ? (a > bb) : (a < bb);
          if (sw) {
            sval[i] = bb; sval[ixj] = a;
            int t = spay[i]; spay[i] = spay[ixj]; spay[ixj] = t;
          }
        }
      }
      __syncthreads();
    }
  }
  for (int i = tid; i < Epad; i += 1024) {
    E1_g[i] = (i < N) ? expf(sval[i]) : 0.f;
    E02_g[i] = (i < N) ? expf(0.2f * sval[i]) : 0.f;
    perm_g[i] = spay[i];
  }
  __syncthreads();
  for (int t = tid; t <= NB; t += 1024) cnt[t] = 0;
  __syncthreads();
  int* kil = spay;  // reuse (perm already written)
  for (int r = tid; r < N; r += 1024) {
    int tok;
    if (mode == 0) {
      int b = r >> 5, l = r & 31;
      tok = (m < NC) ? cand[b * (NC * NL) + m * NL + l]
                     : clicked[b * (NH * NL) + (m - NC) * NL + l];
    } else tok = r;
    float tau = -s1src[tok];
    int lo = 0, hi = N;
    while (lo < hi) { int mid = (lo + hi) >> 1; if (sval[mid] <= tau) lo = mid + 1; else hi = mid; }
    kil[r] = lo;
    atomicAdd(&cnt[lo >> 4], 1);
  }
  __syncthreads();
  if (tid == 0) {
    int run = 0;
    for (int t = 0; t <= NB; ++t) { ofs[t] = run; run += cnt[t]; cnt[t] = ofs[t]; }
  }
  __syncthreads();
  int* rlist_g = rlist + (size_t)m * N;
  float* rs1_g = rs1 + (size_t)m * N;
  for (int r = tid; r < N; r += 1024) {
    int ki = kil[r];
    int pos = atomicAdd(&cnt[ki >> 4], 1);
    rlist_g[pos] = (ki << 16) | r;
    int tok;
    if (mode == 0) {
      int b = r >> 5, l = r & 31;
      tok = (m < NC) ? cand[b * (NC * NL) + m * NL + l]
                     : clicked[b * (NH * NL) + (m - NC) * NL + l];
    } else tok = r;
    rs1_g[pos] = s1src[tok];
  }
  int* boff_g = boff + (size_t)m * (NB + 2);
  for (int t = tid; t <= NB; t += 1024) boff_g[t] = ofs[t];
  if (tid == 0) boff_g[NB + 1] = N;
}

// ---------------------------------------------------------------------------
// Chunked weighted prefix accumulation (local prefixes) + chunk totals T.
// ---------------------------------------------------------------------------
__global__ __launch_bounds__(320) void k_scan(const float* __restrict__ base,
                                              const int* __restrict__ perm,
                                              const float* __restrict__ E1,
                                              const float* __restrict__ E02,
                                              float* __restrict__ C1, float* __restrict__ C02,
                                              float* __restrict__ T1, float* __restrict__ T02,
                                              int Epad, int cstride, int nkc) {
  const int g = blockIdx.y, kc = blockIdx.x;
  const int col = threadIdx.x;
  const int* perm_g = perm + (size_t)g * Epad;
  const float* E1_g = E1 + (size_t)g * Epad;
  const float* E02_g = E02 + (size_t)g * Epad;
  float* C1_g = C1 + (size_t)g * cstride * CW;
  float* C02_g = C02 + (size_t)g * cstride * CW;
  const bool datacol = (col < DD);
  const float wden = (col == DD) ? 1.f : 0.f;
  float acc1 = 0.f, acc2 = 0.f;
  const int k0 = kc * 256;
#pragma unroll 8
  for (int kk = 0; kk < 256; ++kk) {
    int k = k0 + kk;
    int tok = perm_g[k];
    float e1 = E1_g[k], e02 = E02_g[k];
    float w = datacol ? base[(size_t)tok * DD + col] : wden;
    acc1 = fmaf(e1, w, acc1);
    acc2 = fmaf(e02, w, acc2);
    if ((kk & 15) == 15) {
      int t = (k + 1) >> 4;
      if (col < CW) { C1_g[(size_t)t * CW + col] = acc1; C02_g[(size_t)t * CW + col] = acc2; }
    }
  }
  if (col < CW) {
    T1[((size_t)g * nkc + kc) * CW + col] = acc1;
    T02[((size_t)g * nkc + kc) * CW + col] = acc2;
  }
}

// ---------------------------------------------------------------------------
// Bucketed GAT row construction with inline prefix fix-up.
// Phase 1: prefetch 16 residual EW rows (concurrent gathers), build levels.
// Phase 2: 4 rows in flight x 80 threads x 4 cols (8-B stores).
// ---------------------------------------------------------------------------
__global__ __launch_bounds__(320) void k_rows2(
    const float* __restrict__ base,
    const int* __restrict__ perm, const float* __restrict__ E1, const float* __restrict__ E02,
    const float* __restrict__ C1, const float* __restrict__ C02,
    const float* __restrict__ T1, const float* __restrict__ T02,
    const int* __restrict__ rlist, const float* __restrict__ rs1,
    const int* __restrict__ boff,
    __hip_bfloat16* __restrict__ gout,
    int N, int NT, int Epad, int NB, int nkc) {
  __shared__ float U1[16][CW];
  __shared__ float U02[16][CW];
  __shared__ int tokL[16];
  __shared__ float e1L[16], e02L[16];
  const int t = blockIdx.x, g = blockIdx.y;
  const int col = threadIdx.x;
  const int* boff_g = boff + (size_t)g * (NB + 2);
  const int i0 = boff_g[t], i1 = boff_g[t + 1];
  if (i0 >= i1) return;
  const int* perm_g = perm + (size_t)g * Epad;
  const float* E1_g = E1 + (size_t)g * Epad;
  const float* E02_g = E02 + (size_t)g * Epad;
  if (col < 16) {
    int idx = t * 16 + col;
    bool v = idx < N;
    tokL[col] = v ? perm_g[idx] : 0;
    e1L[col] = v ? E1_g[idx] : 0.f;
    e02L[col] = v ? E02_g[idx] : 0.f;
  }
  __syncthreads();
  if (col < CW) {
    // inline fix-up: global prefix at t from chunk totals + local prefix
    const int kc = (t == 0) ? 0 : ((t - 1) >> 4);
    float tot1 = 0.f, pre1 = 0.f, pre02 = 0.f;
    for (int c = 0; c < nkc; ++c) {
      float tv = T1[((size_t)g * nkc + c) * CW + col];
      tot1 += tv;
      if (c < kc) pre1 += tv;
    }
    for (int c = 0; c < kc; ++c) pre02 += T02[((size_t)g * nkc + c) * CW + col];
    if (t > 0) {
      pre1 += C1[((size_t)g * (NT + 1) + t) * CW + col];
      pre02 += C02[((size_t)g * (NT + 1) + t) * CW + col];
    }
    float u1 = tot1 - pre1;
    float u02 = pre02;
    // prefetch residual rows (independent loads, high MLP)
    float wv[16];
#pragma unroll
    for (int j = 0; j < 16; ++j) {
      if (col < DD) wv[j] = ((t * 16 + j) < N) ? base[(size_t)tokL[j] * DD + col] : 0.f;
      else wv[j] = (col == DD) ? 1.f : 0.f;
    }
#pragma unroll
    for (int j = 0; j < 16; ++j) {
      U1[j][col] = u1; U02[j][col] = u02;
      u1 = fmaf(-e1L[j], wv[j], u1);
      u02 = fmaf(e02L[j], wv[j], u02);
    }
  }
  __syncthreads();
  const int slot = col / 80, cp = col % 80;
  const int c0 = cp * 4;
  const int* rlist_g = rlist + (size_t)g * N;
  const float* rs1_g = rs1 + (size_t)g * N;
  for (int i = i0 + slot; i < i1; i += 4) {
    int e = rlist_g[i];
    int r = e & 0xffff, nr = (e >> 16) & 15;
    float s1 = rs1_g[i];
    float es1 = expf(s1), es02 = expf(0.2f * s1);
    float den = es1 * U1[nr][DD] + es02 * U02[nr][DD];
    float rden = 1.f / den;
    short ov[4];
#pragma unroll
    for (int q = 0; q < 4; ++q) {
      int c = c0 + q;
      float ev = 0.f;
      if (c < DD) {
        float num = es1 * U1[nr][c] + es02 * U02[nr][c];
        float gg = num * rden;
        ev = (gg > 0.f) ? gg : expm1f(gg);
      }
      __hip_bfloat16 h = __float2bfloat16(ev);
      ov[q] = *(short*)&h;
    }
    *(bf16x4*)(gout + ((size_t)g * N + r) * GSTR + c0) = *(bf16x4*)ov;
  }
}

// ---------------------------------------------------------------------------
// Fused news logits + additive attention. Block = 64 rows = 2 (b,m) groups.
// Logits via bf16 MFMA; softmax per 32-group; weighted row-sum reuses the
// A-fragments in registers (no g re-read).
// ---------------------------------------------------------------------------
__global__ __launch_bounds__(256) void k_logits_attn(
    const __hip_bfloat16* __restrict__ g, const __hip_bfloat16* __restrict__ Bp,
    const float* __restrict__ lin_b, const float* __restrict__ query,
    float* __restrict__ cand_enc, float* __restrict__ clicked_enc) {
  __shared__ float lg[64];
  __shared__ float wgt[64];
  __shared__ float accw[4][GSTR];
  const int tid = threadIdx.x;
  const int wave = tid >> 6, lane = tid & 63;
  const int quad = lane >> 4, l16 = lane & 15;
  const int m = blockIdx.x >> 5;            // 32 blocks per gat
  const int rbase = (blockIdx.x & 31) * 64; // row within gat
  const __hip_bfloat16* grow =
      g + ((size_t)m * NROW + rbase + wave * 16 + l16) * GSTR + quad * 8;
  bf16x8 afr[KTILES];
#pragma unroll
  for (int kt = 0; kt < KTILES; ++kt) afr[kt] = *(const bf16x8*)(grow + kt * 32);
  float part[4] = {0.f, 0.f, 0.f, 0.f};
  for (int nt = 0; nt < NTILES_N; ++nt) {
    f32x4 acc = {0.f, 0.f, 0.f, 0.f};
    const bf16x8* bp = (const bf16x8*)Bp + (size_t)nt * KTILES * 64 + lane;
#pragma unroll
    for (int kt = 0; kt < KTILES; ++kt)
      acc = __builtin_amdgcn_mfma_f32_16x16x32_bf16(afr[kt], bp[kt * 64], acc, 0, 0, 0);
    const int n = nt * 16 + l16;
    const float qv = (n < QQ) ? query[n] : 0.f;
    const float bv = (n < QQ) ? lin_b[n] : 0.f;
#pragma unroll
    for (int r = 0; r < 4; ++r)
      part[r] = fmaf(tanhf(acc[r] + bv), qv, part[r]);
  }
#pragma unroll
  for (int r = 0; r < 4; ++r) {
    float p = part[r];
    p += __shfl_xor(p, 1, 64); p += __shfl_xor(p, 2, 64);
    p += __shfl_xor(p, 4, 64); p += __shfl_xor(p, 8, 64);
    if (l16 == 0) lg[wave * 16 + quad * 4 + r] = p;
  }
  __syncthreads();
  if (tid < 64) {  // softmax per 32-group (xor<=16 stays within the group)
    float v = lg[tid];
    float mx = v;
    mx = fmaxf(mx, __shfl_xor(mx, 1, 64)); mx = fmaxf(mx, __shfl_xor(mx, 2, 64));
    mx = fmaxf(mx, __shfl_xor(mx, 4, 64)); mx = fmaxf(mx, __shfl_xor(mx, 8, 64));
    mx = fmaxf(mx, __shfl_xor(mx, 16, 64));
    float e = expf(v - mx), sm = e;
    sm += __shfl_xor(sm, 1, 64); sm += __shfl_xor(sm, 2, 64);
    sm += __shfl_xor(sm, 4, 64); sm += __shfl_xor(sm, 8, 64);
    sm += __shfl_xor(sm, 16, 64);
    wgt[tid] = e / sm;
  }
  __syncthreads();
  const float w = wgt[wave * 16 + l16];
#pragma unroll
  for (int kt = 0; kt < KTILES; ++kt) {
#pragma unroll
    for (int j = 0; j < 8; ++j) {
      float v = bf2f(afr[kt][j]) * w;
      v += __shfl_xor(v, 1, 64); v += __shfl_xor(v, 2, 64);
      v += __shfl_xor(v, 4, 64); v += __shfl_xor(v, 8, 64);
      if (l16 == 0) accw[wave][kt * 32 + quad * 8 + j] = v;
    }
  }
  __syncthreads();
  const int b0 = rbase >> 5;
  float* o0 = (m < NC) ? (cand_enc + ((size_t)b0 * NC + m) * DD)
                       : (clicked_enc + ((size_t)b0 * NH + (m - NC)) * DD);
  float* o1 = (m < NC) ? (cand_enc + ((size_t)(b0 + 1) * NC + m) * DD)
                       : (clicked_enc + ((size_t)(b0 + 1) * NH + (m - NC)) * DD);
  for (int c = tid; c < DD; c += 256) {
    o0[c] = accw[0][c] + accw[1][c];
    o1[c] = accw[2][c] + accw[3][c];
  }
}

// ---------------------------------------------------------------------------
// Fused user logits + attention + click-score dot. Block = one b (50 rows).
// ---------------------------------------------------------------------------
__global__ __launch_bounds__(256) void k_user_attn(
    const __hip_bfloat16* __restrict__ g, const __hip_bfloat16* __restrict__ Bp,
    const float* __restrict__ lin_b, const float* __restrict__ query,
    const float* __restrict__ cand_enc, float* __restrict__ out) {
  __shared__ float lg[64];
  __shared__ float wgt[64];
  __shared__ float accw[4][GSTR];
  __shared__ float uenc[CW];
  __shared__ float wred[4];
  const int b = blockIdx.x, tid = threadIdx.x;
  const int wave = tid >> 6, lane = tid & 63;
  const int quad = lane >> 4, l16 = lane & 15;
  const int rl = wave * 16 + l16;
  const int rclamp = (rl < NH) ? rl : 0;
  const __hip_bfloat16* grow = g + ((size_t)b * NH + rclamp) * GSTR + quad * 8;
  bf16x8 afr[KTILES];
#pragma unroll
  for (int kt = 0; kt < KTILES; ++kt) afr[kt] = *(const bf16x8*)(grow + kt * 32);
  float part[4] = {0.f, 0.f, 0.f, 0.f};
  for (int nt = 0; nt < NTILES_N; ++nt) {
    f32x4 acc = {0.f, 0.f, 0.f, 0.f};
    const bf16x8* bp = (const bf16x8*)Bp + (size_t)nt * KTILES * 64 + lane;
#pragma unroll
    for (int kt = 0; kt < KTILES; ++kt)
      acc = __builtin_amdgcn_mfma_f32_16x16x32_bf16(afr[kt], bp[kt * 64], acc, 0, 0, 0);
    const int n = nt * 16 + l16;
    const float qv = (n < QQ) ? query[n] : 0.f;
    const float bv = (n < QQ) ? lin_b[n] : 0.f;
#pragma unroll
    for (int r = 0; r < 4; ++r)
      part[r] = fmaf(tanhf(acc[r] + bv), qv, part[r]);
  }
#pragma unroll
  for (int r = 0; r < 4; ++r) {
    float p = part[r];
    p += __shfl_xor(p, 1, 64); p += __shfl_xor(p, 2, 64);
    p += __shfl_xor(p, 4, 64); p += __shfl_xor(p, 8, 64);
    if (l16 == 0) lg[wave * 16 + quad * 4 + r] = p;
  }
  __syncthreads();
  if (tid < 64) {  // softmax over 50 valid rows (full 64-lane reduction)
    float v = (tid < NH) ? lg[tid] : -3.4e38f;
    float mx = v;
    for (int o = 32; o; o >>= 1) mx = fmaxf(mx, __shfl_xor(mx, o, 64));
    float e = (tid < NH) ? expf(v - mx) : 0.f;
    float sm = e;
    for (int o = 32; o; o >>= 1) sm += __shfl_xor(sm, o, 64);
    wgt[tid] = (tid < NH) ? e / sm : 0.f;
  }
  __syncthreads();
  const float w = (rl < NH) ? wgt[rl] : 0.f;
#pragma unroll
  for (int kt = 0; kt < KTILES; ++kt) {
#pragma unroll
    for (int j = 0; j < 8; ++j) {
      float v = bf2f(afr[kt][j]) * w;
      v += __shfl_xor(v, 1, 64); v += __shfl_xor(v, 2, 64);
      v += __shfl_xor(v, 4, 64); v += __shfl_xor(v, 8, 64);
      if (l16 == 0) accw[wave][kt * 32 + quad * 8 + j] = v;
    }
  }
  __syncthreads();
  for (int c = tid; c < DD; c += 256)
    uenc[c] = accw[0][c] + accw[1][c] + accw[2][c] + accw[3][c];
  __syncthreads();
  // click scores for this b
  for (int c5 = 0; c5 < NC; ++c5) {
    const float* cp = cand_enc + ((size_t)b * NC + c5) * DD;
    float s = 0.f;
    for (int d = tid; d < DD; d += 256) s = fmaf(uenc[d], cp[d], s);
    for (int o = 32; o; o >>= 1) s += __shfl_xor(s, o, 64);
    if (lane == 0) wred[wave] = s;
    __syncthreads();
    if (tid == 0) out[b * NC + c5] = wred[0] + wred[1] + wred[2] + wred[3];
    __syncthreads();
  }
}

// ---------------------------------------------------------------------------
extern "C" void kernel_launch(void* const* d_in, const int* in_sizes, int n_in,
                              void* d_out, int out_size, void* d_ws, size_t ws_size,
                              hipStream_t stream) {
  const int* cand = (const int*)d_in[0];
  const int* clicked = (const int*)d_in[1];
  const float* emb = (const float*)d_in[2];
  const float* news_W = (const float*)d_in[3];
  const float* news_a = (const float*)d_in[4];
  const float* news_lw = (const float*)d_in[5];
  const float* news_lb = (const float*)d_in[6];
  const float* news_q = (const float*)d_in[7];
  const float* user_W = (const float*)d_in[8];
  const float* user_a = (const float*)d_in[9];
  const float* user_lw = (const float*)d_in[10];
  const float* user_lb = (const float*)d_in[11];
  const float* user_q = (const float*)d_in[12];
  float* out = (float*)d_out;

  float* W = (float*)d_ws;
  size_t o = 0;
  auto nxt = [&](size_t n) { size_t c = o; o += (n + 63) & ~(size_t)63; return c; };
  float* EW = W + nxt((size_t)NVOC * DD);
  float* s1v = W + nxt(NVOC);
  float* s2v = W + nxt(NVOC);
  int* perm = (int*)(W + nxt((size_t)NGAT * NROW));
  float* E1 = W + nxt((size_t)NGAT * NROW);
  float* E02 = W + nxt((size_t)NGAT * NROW);
  float* C1 = W + nxt((size_t)NGAT * (NT_NEWS + 1) * CW);
  float* C02 = W + nxt((size_t)NGAT * (NT_NEWS + 1) * CW);
  float* T1N = W + nxt((size_t)NGAT * 8 * CW);
  float* T02N = W + nxt((size_t)NGAT * 8 * CW);
  int* rlistN = (int*)(W + nxt((size_t)NGAT * NROW));
  float* rs1N = W + nxt((size_t)NGAT * NROW);
  int* boffN = (int*)(W + nxt((size_t)NGAT * (NB_NEWS + 2)));
  float* cand_enc = W + nxt((size_t)BN_B * NC * DD);
  float* clicked_enc = W + nxt((size_t)BN_B * NH * DD);
  float* WhU = W + nxt((size_t)NUSR * DD);
  float* s1u = W + nxt(NUSR);
  float* s2u = W + nxt(NUSR);
  int* permU = (int*)(W + nxt(NUSR_PAD));
  float* E1U = W + nxt(NUSR_PAD);
  float* E02U = W + nxt(NUSR_PAD);
  float* C1U = W + nxt((size_t)(NT_USER + 1) * CW);
  float* C02U = W + nxt((size_t)(NT_USER + 1) * CW);
  float* T1U = W + nxt((size_t)13 * CW);
  float* T02U = W + nxt((size_t)13 * CW);
  int* rlistU = (int*)(W + nxt(NUSR));
  float* rs1U = W + nxt(NUSR);
  int* boffU = (int*)(W + nxt(NB_USER + 2));
  __hip_bfloat16* BpN = (__hip_bfloat16*)(W + nxt((size_t)BPELT * 8 / 2));
  __hip_bfloat16* BpU = (__hip_bfloat16*)(W + nxt((size_t)BPELT * 8 / 2));
  __hip_bfloat16* WhiN = (__hip_bfloat16*)(W + nxt((size_t)WPELT * 8 / 2));
  __hip_bfloat16* WloN = (__hip_bfloat16*)(W + nxt((size_t)WPELT * 8 / 2));
  __hip_bfloat16* WhiU = (__hip_bfloat16*)(W + nxt((size_t)WPELT * 8 / 2));
  __hip_bfloat16* WloU = (__hip_bfloat16*)(W + nxt((size_t)WPELT * 8 / 2));
  __hip_bfloat16* g_news = (__hip_bfloat16*)(W + nxt((size_t)NGAT * NROW * GSTR / 2));
  __hip_bfloat16* g_user = (__hip_bfloat16*)(W + nxt((size_t)NUSR * GSTR / 2));

  const int packgrid = (BPELT + 255) / 256;
  const int packWgrid = (WPELT + 255) / 256;

  // 1. packs (news+user in one launch each)
  k_packW<<<dim3(packWgrid, 2), 256, 0, stream>>>(news_W, user_W, WhiN, WloN, WhiU, WloU);
  k_packB<<<dim3(packgrid, 2), 256, 0, stream>>>(news_lw, user_lw, BpN, BpU);
  // 2. EW = emb @ news_W  (+ fused s1/s2)
  k_gemm_mfma<<<(NVOC + 63) / 64, 256, 0, stream>>>(emb, WhiN, WloN, news_a, EW, s1v, s2v, NVOC);
  // 3. sort + exp tables + rank/bucket per news GAT
  k_sort2<<<NGAT, 1024, 0, stream>>>(cand, clicked, s2v, s1v, perm, E1, E02,
                                     rlistN, rs1N, boffN, 0, NROW, NROW, NROW, NB_NEWS);
  // 4. coarse weighted prefix sums (local) + totals
  k_scan<<<dim3(8, NGAT), 320, 0, stream>>>(EW, perm, E1, E02, C1, C02, T1N, T02N,
                                            NROW, NT_NEWS + 1, 8);
  // 5. bucketed GAT rows (inline fix-up) -> g_news
  k_rows2<<<dim3(NB_NEWS + 1, NGAT), 320, 0, stream>>>(EW, perm, E1, E02, C1, C02, T1N, T02N,
                                                       rlistN, rs1N, boffN, g_news,
                                                       NROW, NT_NEWS, NROW, NB_NEWS, 8);
  // 6. fused logits+attention -> cand/clicked encodings
  k_logits_attn<<<NGAT * NROW / 64, 256, 0, stream>>>(g_news, BpN, news_lb, news_q,
                                                      cand_enc, clicked_enc);
  // 7-10. user GAT
  k_gemm_mfma<<<(NUSR + 63) / 64, 256, 0, stream>>>(clicked_enc, WhiU, WloU, user_a,
                                                    WhU, s1u, s2u, NUSR);
  k_sort2<<<1, 1024, 0, stream>>>(nullptr, nullptr, s2u, s1u, permU, E1U, E02U,
                                  rlistU, rs1U, boffU, 1, NUSR, 4096, NUSR_PAD, NB_USER);
  k_scan<<<dim3(13, 1), 320, 0, stream>>>(WhU, permU, E1U, E02U, C1U, C02U, T1U, T02U,
                                          NUSR_PAD, NT_USER + 1, 13);
  k_rows2<<<dim3(NB_USER + 1, 1), 320, 0, stream>>>(WhU, permU, E1U, E02U, C1U, C02U, T1U, T02U,
                                                    rlistU, rs1U, boffU, g_user,
                                                    NUSR, NT_USER, NUSR_PAD, NB_USER, 13);
  // 11. fused user logits + attention + click score
  k_user_attn<<<BN_B, 256, 0, stream>>>(g_user, BpU, user_lb, user_q, cand_enc, out);
}

// Round 7
// 778.674 us; speedup vs baseline: 1.1381x; 1.0116x over previous
//
#include <hip/hip_runtime.h>
#include <hip/hip_bf16.h>

// Problem constants
#define BN_B 64
#define NC 5
#define NH 50
#define NL 32
#define DD 300
#define QQ 200
#define NVOC 50000
#define NGAT 55          // 5 candidate + 50 clicked news GATs
#define NROW 2048        // rows per news GAT (B*L)
#define NUSR 3200        // rows user GAT (B*H)
#define NUSR_PAD 3328    // 13*256
#define CW 304           // prefix array row width (300 data + col300 = denominator)
#define NT_NEWS 128      // 2048/16
#define NT_USER 208      // 3328/16
#define NB_NEWS 128      // max bucket index = NROW/16
#define NB_USER 200      // max bucket index = NUSR/16
#define GSTR 320         // padded g row stride (10 K-tiles of 32 for MFMA)
#define NTILES_N 13      // ceil(200/16)
#define KTILES 10        // 320/32
#define BPELT (NTILES_N * KTILES * 64)  // B-fragment entries (x8 bf16 each)
#define WNT 19
#define WKT 10
#define WPELT (WNT * WKT * 64)

typedef short bf16x8 __attribute__((ext_vector_type(8)));
typedef short bf16x4 __attribute__((ext_vector_type(4)));
typedef float f32x4 __attribute__((ext_vector_type(4)));

static __device__ __forceinline__ float bf2f(short s) {
  return __uint_as_float(((unsigned)(unsigned short)s) << 16);
}

// ---------------------------------------------------------------------------
// Pack W [300,300] fp32 -> split bf16 (hi/lo) B-fragments. y = 0 news, 1 user.
// ---------------------------------------------------------------------------
__global__ __launch_bounds__(256) void k_packW(const float* __restrict__ W0,
                                               const float* __restrict__ W1,
                                               __hip_bfloat16* __restrict__ h0,
                                               __hip_bfloat16* __restrict__ l0,
                                               __hip_bfloat16* __restrict__ h1,
                                               __hip_bfloat16* __restrict__ l1) {
  const float* Wm = blockIdx.y ? W1 : W0;
  __hip_bfloat16* Bhi = blockIdx.y ? h1 : h0;
  __hip_bfloat16* Blo = blockIdx.y ? l1 : l0;
  int e = blockIdx.x * 256 + threadIdx.x;
  if (e >= WPELT) return;
  int lane = e & 63, nt = (e >> 6) % WNT, kt = (e >> 6) / WNT;
  int n = nt * 16 + (lane & 15);
  int k0 = kt * 32 + (lane >> 4) * 8;
  __hip_bfloat16 hv[8], lv[8];
#pragma unroll
  for (int j = 0; j < 8; ++j) {
    int k = k0 + j;
    float v = (k < DD && n < DD) ? Wm[(size_t)k * DD + n] : 0.f;
    __hip_bfloat16 h = __float2bfloat16(v);
    hv[j] = h;
    lv[j] = __float2bfloat16(v - __bfloat162float(h));
  }
  *(bf16x8*)(Bhi + (size_t)e * 8) = *(const bf16x8*)hv;
  *(bf16x8*)(Blo + (size_t)e * 8) = *(const bf16x8*)lv;
}

// Pack lin_w [Q,300] -> bf16 B-fragments, KT-MAJOR: e = (kt*NTILES_N+nt)*64+lane
// so the consumer's nt-inner loop walks consecutive 1-KB fragments.
__global__ __launch_bounds__(256) void k_packB(const float* __restrict__ lw0,
                                               const float* __restrict__ lw1,
                                               __hip_bfloat16* __restrict__ B0,
                                               __hip_bfloat16* __restrict__ B1) {
  const float* lw = blockIdx.y ? lw1 : lw0;
  __hip_bfloat16* Bp = blockIdx.y ? B1 : B0;
  int e = blockIdx.x * 256 + threadIdx.x;
  if (e >= BPELT) return;
  int lane = e & 63, nt = (e >> 6) % NTILES_N, kt = (e >> 6) / NTILES_N;
  int n = nt * 16 + (lane & 15);
  int k0 = kt * 32 + (lane >> 4) * 8;
  __hip_bfloat16 vals[8];
#pragma unroll
  for (int j = 0; j < 8; ++j) {
    int k = k0 + j;
    float v = (n < QQ && k < DD) ? lw[(size_t)n * DD + k] : 0.f;
    vals[j] = __float2bfloat16(v);
  }
  *(bf16x8*)(Bp + (size_t)e * 8) = *(const bf16x8*)vals;
}

// ---------------------------------------------------------------------------
// C[M,300] = A[M,300] @ W[300,300] via split-bf16 MFMA (3 products ~ fp32),
// fused epilogue: s1[row]=C·avec[0:300], s2[row]=C·avec[300:600].
// ---------------------------------------------------------------------------
__global__ __launch_bounds__(256) void k_gemm_mfma(const float* __restrict__ A,
                                                   const __hip_bfloat16* __restrict__ Bhi,
                                                   const __hip_bfloat16* __restrict__ Blo,
                                                   const float* __restrict__ avec,
                                                   float* __restrict__ C,
                                                   float* __restrict__ s1o,
                                                   float* __restrict__ s2o, int M) {
  const int tid = threadIdx.x;
  const int wave = tid >> 6, lane = tid & 63;
  const int quad = lane >> 4, l16 = lane & 15;
  const int rowA = blockIdx.x * 64 + wave * 16 + l16;
  const float* ar = A + (size_t)rowA * DD;
  f32x4 acc[WNT];
#pragma unroll
  for (int nt = 0; nt < WNT; ++nt) acc[nt] = (f32x4){0.f, 0.f, 0.f, 0.f};

  for (int kt = 0; kt < WKT; ++kt) {
    const int k0 = kt * 32 + quad * 8;
    float av[8];
    if (rowA < M && k0 + 8 <= DD) {
      float4 v0 = *(const float4*)(ar + k0);
      float4 v1 = *(const float4*)(ar + k0 + 4);
      av[0] = v0.x; av[1] = v0.y; av[2] = v0.z; av[3] = v0.w;
      av[4] = v1.x; av[5] = v1.y; av[6] = v1.z; av[7] = v1.w;
    } else {
#pragma unroll
      for (int j = 0; j < 8; ++j) {
        int k = k0 + j;
        av[j] = (rowA < M && k < DD) ? ar[k] : 0.f;
      }
    }
    __hip_bfloat16 hv[8], lv[8];
#pragma unroll
    for (int j = 0; j < 8; ++j) {
      __hip_bfloat16 h = __float2bfloat16(av[j]);
      hv[j] = h;
      lv[j] = __float2bfloat16(av[j] - __bfloat162float(h));
    }
    const bf16x8 ah = *(const bf16x8*)hv;
    const bf16x8 al = *(const bf16x8*)lv;
    const bf16x8* bh = (const bf16x8*)Bhi + (size_t)(kt * WNT) * 64 + lane;
    const bf16x8* bl = (const bf16x8*)Blo + (size_t)(kt * WNT) * 64 + lane;
#pragma unroll
    for (int nt = 0; nt < WNT; ++nt) {
      bf16x8 bhf = bh[nt * 64], blf = bl[nt * 64];
      acc[nt] = __builtin_amdgcn_mfma_f32_16x16x32_bf16(ah, bhf, acc[nt], 0, 0, 0);
      acc[nt] = __builtin_amdgcn_mfma_f32_16x16x32_bf16(al, bhf, acc[nt], 0, 0, 0);
      acc[nt] = __builtin_amdgcn_mfma_f32_16x16x32_bf16(ah, blf, acc[nt], 0, 0, 0);
    }
  }
  const int mbase = blockIdx.x * 64 + wave * 16 + quad * 4;
#pragma unroll
  for (int nt = 0; nt < WNT; ++nt) {
    int n = nt * 16 + l16;
    if (n < DD) {
#pragma unroll
      for (int r = 0; r < 4; ++r) {
        int mr = mbase + r;
        if (mr < M) C[(size_t)mr * DD + n] = acc[nt][r];
      }
    }
  }
  // s1/s2 epilogue
  float a1v[WNT], a2v[WNT];
#pragma unroll
  for (int nt = 0; nt < WNT; ++nt) {
    int n = nt * 16 + l16;
    a1v[nt] = (n < DD) ? avec[n] : 0.f;
    a2v[nt] = (n < DD) ? avec[DD + n] : 0.f;
  }
#pragma unroll
  for (int r = 0; r < 4; ++r) {
    float p1 = 0.f, p2 = 0.f;
#pragma unroll
    for (int nt = 0; nt < WNT; ++nt) {
      p1 = fmaf(acc[nt][r], a1v[nt], p1);
      p2 = fmaf(acc[nt][r], a2v[nt], p2);
    }
    p1 += __shfl_xor(p1, 1, 64); p1 += __shfl_xor(p1, 2, 64);
    p1 += __shfl_xor(p1, 4, 64); p1 += __shfl_xor(p1, 8, 64);
    p2 += __shfl_xor(p2, 1, 64); p2 += __shfl_xor(p2, 2, 64);
    p2 += __shfl_xor(p2, 4, 64); p2 += __shfl_xor(p2, 8, 64);
    int mr = mbase + r;
    if (l16 == 0 && mr < M) { s1o[mr] = p1; s2o[mr] = p2; }
  }
}

// ---------------------------------------------------------------------------
// Bitonic sort of s2 + exp tables + rank/bucket epilogue.
// ---------------------------------------------------------------------------
__global__ __launch_bounds__(1024) void k_sort2(const int* __restrict__ cand,
                                                const int* __restrict__ clicked,
                                                const float* __restrict__ s2src,
                                                const float* __restrict__ s1src,
                                                int* __restrict__ perm,
                                                float* __restrict__ E1, float* __restrict__ E02,
                                                int* __restrict__ rlist, float* __restrict__ rs1,
                                                int* __restrict__ boff,
                                                int mode, int N, int SZ, int Epad, int NB) {
  __shared__ float sval[4096];
  __shared__ int spay[4096];
  __shared__ int cnt[224];
  __shared__ int ofs[224];
  const int m = blockIdx.x;
  const int tid = threadIdx.x;
  int* perm_g = perm + (size_t)m * Epad;
  float* E1_g = E1 + (size_t)m * Epad;
  float* E02_g = E02 + (size_t)m * Epad;

  for (int i = tid; i < SZ; i += 1024) {
    float v; int p;
    if (mode == 0) {
      int b = i >> 5, l = i & 31;
      int tok = (m < NC) ? cand[b * (NC * NL) + m * NL + l]
                         : clicked[b * (NH * NL) + (m - NC) * NL + l];
      v = s2src[tok]; p = tok;
    } else {
      if (i < N) { v = s2src[i]; p = i; } else { v = __builtin_inff(); p = 0; }
    }
    sval[i] = v; spay[i] = p;
  }
  __syncthreads();
  for (int k = 2; k <= SZ; k <<= 1) {
    for (int j = k >> 1; j > 0; j >>= 1) {
      for (int i = tid; i < SZ; i += 1024) {
        int ixj = i ^ j;
        if (ixj > i) {
          bool asc = ((i & k) == 0);
          float a = sval[i], bb = sval[ixj];
          bool sw = asc ? (a > bb) : (a < bb);
          if (sw) {
            sval[i] = bb; sval[ixj] = a;
            int t = spay[i]; spay[i] = spay[ixj]; spay[ixj] = t;
          }
        }
      }
      __syncthreads();
    }
  }
  for (int i = tid; i < Epad; i += 1024) {
    E1_g[i] = (i < N) ? expf(sval[i]) : 0.f;
    E02_g[i] = (i < N) ? expf(0.2f * sval[i]) : 0.f;
    perm_g[i] = spay[i];
  }
  __syncthreads();
  for (int t = tid; t <= NB; t += 1024) cnt[t] = 0;
  __syncthreads();
  int* kil = spay;  // reuse (perm already written)
  for (int r = tid; r < N; r += 1024) {
    int tok;
    if (mode == 0) {
      int b = r >> 5, l = r & 31;
      tok = (m < NC) ? cand[b * (NC * NL) + m * NL + l]
                     : clicked[b * (NH * NL) + (m - NC) * NL + l];
    } else tok = r;
    float tau = -s1src[tok];
    int lo = 0, hi = N;
    while (lo < hi) { int mid = (lo + hi) >> 1; if (sval[mid] <= tau) lo = mid + 1; else hi = mid; }
    kil[r] = lo;
    atomicAdd(&cnt[lo >> 4], 1);
  }
  __syncthreads();
  if (tid == 0) {
    int run = 0;
    for (int t = 0; t <= NB; ++t) { ofs[t] = run; run += cnt[t]; cnt[t] = ofs[t]; }
  }
  __syncthreads();
  int* rlist_g = rlist + (size_t)m * N;
  float* rs1_g = rs1 + (size_t)m * N;
  for (int r = tid; r < N; r += 1024) {
    int ki = kil[r];
    int pos = atomicAdd(&cnt[ki >> 4], 1);
    rlist_g[pos] = (ki << 16) | r;
    int tok;
    if (mode == 0) {
      int b = r >> 5, l = r & 31;
      tok = (m < NC) ? cand[b * (NC * NL) + m * NL + l]
                     : clicked[b * (NH * NL) + (m - NC) * NL + l];
    } else tok = r;
    rs1_g[pos] = s1src[tok];
  }
  int* boff_g = boff + (size_t)m * (NB + 2);
  for (int t = tid; t <= NB; t += 1024) boff_g[t] = ofs[t];
  if (tid == 0) boff_g[NB + 1] = N;
}

// ---------------------------------------------------------------------------
// Chunked weighted prefix accumulation (local prefixes) + chunk totals T.
// ---------------------------------------------------------------------------
__global__ __launch_bounds__(320) void k_scan(const float* __restrict__ base,
                                              const int* __restrict__ perm,
                                              const float* __restrict__ E1,
                                              const float* __restrict__ E02,
                                              float* __restrict__ C1, float* __restrict__ C02,
                                              float* __restrict__ T1, float* __restrict__ T02,
                                              int Epad, int cstride, int nkc) {
  const int g = blockIdx.y, kc = blockIdx.x;
  const int col = threadIdx.x;
  const int* perm_g = perm + (size_t)g * Epad;
  const float* E1_g = E1 + (size_t)g * Epad;
  const float* E02_g = E02 + (size_t)g * Epad;
  float* C1_g = C1 + (size_t)g * cstride * CW;
  float* C02_g = C02 + (size_t)g * cstride * CW;
  const bool datacol = (col < DD);
  const float wden = (col == DD) ? 1.f : 0.f;
  float acc1 = 0.f, acc2 = 0.f;
  const int k0 = kc * 256;
#pragma unroll 8
  for (int kk = 0; kk < 256; ++kk) {
    int k = k0 + kk;
    int tok = perm_g[k];
    float e1 = E1_g[k], e02 = E02_g[k];
    float w = datacol ? base[(size_t)tok * DD + col] : wden;
    acc1 = fmaf(e1, w, acc1);
    acc2 = fmaf(e02, w, acc2);
    if ((kk & 15) == 15) {
      int t = (k + 1) >> 4;
      if (col < CW) { C1_g[(size_t)t * CW + col] = acc1; C02_g[(size_t)t * CW + col] = acc2; }
    }
  }
  if (col < CW) {
    T1[((size_t)g * nkc + kc) * CW + col] = acc1;
    T02[((size_t)g * nkc + kc) * CW + col] = acc2;
  }
}

// ---------------------------------------------------------------------------
// Bucketed GAT row construction with inline prefix fix-up.
// ---------------------------------------------------------------------------
__global__ __launch_bounds__(320) void k_rows2(
    const float* __restrict__ base,
    const int* __restrict__ perm, const float* __restrict__ E1, const float* __restrict__ E02,
    const float* __restrict__ C1, const float* __restrict__ C02,
    const float* __restrict__ T1, const float* __restrict__ T02,
    const int* __restrict__ rlist, const float* __restrict__ rs1,
    const int* __restrict__ boff,
    __hip_bfloat16* __restrict__ gout,
    int N, int NT, int Epad, int NB, int nkc) {
  __shared__ float U1[16][CW];
  __shared__ float U02[16][CW];
  __shared__ int tokL[16];
  __shared__ float e1L[16], e02L[16];
  const int t = blockIdx.x, g = blockIdx.y;
  const int col = threadIdx.x;
  const int* boff_g = boff + (size_t)g * (NB + 2);
  const int i0 = boff_g[t], i1 = boff_g[t + 1];
  if (i0 >= i1) return;
  const int* perm_g = perm + (size_t)g * Epad;
  const float* E1_g = E1 + (size_t)g * Epad;
  const float* E02_g = E02 + (size_t)g * Epad;
  if (col < 16) {
    int idx = t * 16 + col;
    bool v = idx < N;
    tokL[col] = v ? perm_g[idx] : 0;
    e1L[col] = v ? E1_g[idx] : 0.f;
    e02L[col] = v ? E02_g[idx] : 0.f;
  }
  __syncthreads();
  if (col < CW) {
    const int kc = (t == 0) ? 0 : ((t - 1) >> 4);
    float tot1 = 0.f, pre1 = 0.f, pre02 = 0.f;
    for (int c = 0; c < nkc; ++c) {
      float tv = T1[((size_t)g * nkc + c) * CW + col];
      tot1 += tv;
      if (c < kc) pre1 += tv;
    }
    for (int c = 0; c < kc; ++c) pre02 += T02[((size_t)g * nkc + c) * CW + col];
    if (t > 0) {
      pre1 += C1[((size_t)g * (NT + 1) + t) * CW + col];
      pre02 += C02[((size_t)g * (NT + 1) + t) * CW + col];
    }
    float u1 = tot1 - pre1;
    float u02 = pre02;
    float wv[16];
#pragma unroll
    for (int j = 0; j < 16; ++j) {
      if (col < DD) wv[j] = ((t * 16 + j) < N) ? base[(size_t)tokL[j] * DD + col] : 0.f;
      else wv[j] = (col == DD) ? 1.f : 0.f;
    }
#pragma unroll
    for (int j = 0; j < 16; ++j) {
      U1[j][col] = u1; U02[j][col] = u02;
      u1 = fmaf(-e1L[j], wv[j], u1);
      u02 = fmaf(e02L[j], wv[j], u02);
    }
  }
  __syncthreads();
  const int slot = col / 80, cp = col % 80;
  const int c0 = cp * 4;
  const int* rlist_g = rlist + (size_t)g * N;
  const float* rs1_g = rs1 + (size_t)g * N;
  for (int i = i0 + slot; i < i1; i += 4) {
    int e = rlist_g[i];
    int r = e & 0xffff, nr = (e >> 16) & 15;
    float s1 = rs1_g[i];
    float es1 = expf(s1), es02 = expf(0.2f * s1);
    float den = es1 * U1[nr][DD] + es02 * U02[nr][DD];
    float rden = 1.f / den;
    short ov[4];
#pragma unroll
    for (int q = 0; q < 4; ++q) {
      int c = c0 + q;
      float ev = 0.f;
      if (c < DD) {
        float num = es1 * U1[nr][c] + es02 * U02[nr][c];
        float gg = num * rden;
        ev = (gg > 0.f) ? gg : expm1f(gg);
      }
      __hip_bfloat16 h = __float2bfloat16(ev);
      ov[q] = *(short*)&h;
    }
    *(bf16x4*)(gout + ((size_t)g * N + r) * GSTR + c0) = *(bf16x4*)ov;
  }
}

// ---------------------------------------------------------------------------
// Fused news logits + additive attention. Block = 64 rows = 2 (b,m) groups.
// K-loop: kt outer, 13 INDEPENDENT n-tile accumulators inner (short dep chain).
// ---------------------------------------------------------------------------
__global__ __launch_bounds__(256) void k_logits_attn(
    const __hip_bfloat16* __restrict__ g, const __hip_bfloat16* __restrict__ Bp,
    const float* __restrict__ lin_b, const float* __restrict__ query,
    float* __restrict__ cand_enc, float* __restrict__ clicked_enc) {
  __shared__ float lg[64];
  __shared__ float wgt[64];
  __shared__ float accw[4][GSTR];
  const int tid = threadIdx.x;
  const int wave = tid >> 6, lane = tid & 63;
  const int quad = lane >> 4, l16 = lane & 15;
  const int m = blockIdx.x >> 5;            // 32 blocks per gat
  const int rbase = (blockIdx.x & 31) * 64; // row within gat
  const __hip_bfloat16* grow =
      g + ((size_t)m * NROW + rbase + wave * 16 + l16) * GSTR + quad * 8;
  bf16x8 afr[KTILES];
#pragma unroll
  for (int kt = 0; kt < KTILES; ++kt) afr[kt] = *(const bf16x8*)(grow + kt * 32);
  f32x4 acc[NTILES_N];
#pragma unroll
  for (int nt = 0; nt < NTILES_N; ++nt) acc[nt] = (f32x4){0.f, 0.f, 0.f, 0.f};
  for (int kt = 0; kt < KTILES; ++kt) {
    const bf16x8* bp = (const bf16x8*)Bp + (size_t)kt * NTILES_N * 64 + lane;
#pragma unroll
    for (int nt = 0; nt < NTILES_N; ++nt)
      acc[nt] = __builtin_amdgcn_mfma_f32_16x16x32_bf16(afr[kt], bp[nt * 64], acc[nt], 0, 0, 0);
  }
  float part[4] = {0.f, 0.f, 0.f, 0.f};
#pragma unroll
  for (int nt = 0; nt < NTILES_N; ++nt) {
    const int n = nt * 16 + l16;
    const float qv = (n < QQ) ? query[n] : 0.f;
    const float bv = (n < QQ) ? lin_b[n] : 0.f;
#pragma unroll
    for (int r = 0; r < 4; ++r)
      part[r] = fmaf(tanhf(acc[nt][r] + bv), qv, part[r]);
  }
#pragma unroll
  for (int r = 0; r < 4; ++r) {
    float p = part[r];
    p += __shfl_xor(p, 1, 64); p += __shfl_xor(p, 2, 64);
    p += __shfl_xor(p, 4, 64); p += __shfl_xor(p, 8, 64);
    if (l16 == 0) lg[wave * 16 + quad * 4 + r] = p;
  }
  __syncthreads();
  if (tid < 64) {  // softmax per 32-group (xor<=16 stays within the group)
    float v = lg[tid];
    float mx = v;
    mx = fmaxf(mx, __shfl_xor(mx, 1, 64)); mx = fmaxf(mx, __shfl_xor(mx, 2, 64));
    mx = fmaxf(mx, __shfl_xor(mx, 4, 64)); mx = fmaxf(mx, __shfl_xor(mx, 8, 64));
    mx = fmaxf(mx, __shfl_xor(mx, 16, 64));
    float e = expf(v - mx), sm = e;
    sm += __shfl_xor(sm, 1, 64); sm += __shfl_xor(sm, 2, 64);
    sm += __shfl_xor(sm, 4, 64); sm += __shfl_xor(sm, 8, 64);
    sm += __shfl_xor(sm, 16, 64);
    wgt[tid] = e / sm;
  }
  __syncthreads();
  const float w = wgt[wave * 16 + l16];
#pragma unroll
  for (int kt = 0; kt < KTILES; ++kt) {
#pragma unroll
    for (int j = 0; j < 8; ++j) {
      float v = bf2f(afr[kt][j]) * w;
      v += __shfl_xor(v, 1, 64); v += __shfl_xor(v, 2, 64);
      v += __shfl_xor(v, 4, 64); v += __shfl_xor(v, 8, 64);
      if (l16 == 0) accw[wave][kt * 32 + quad * 8 + j] = v;
    }
  }
  __syncthreads();
  const int b0 = rbase >> 5;
  float* o0 = (m < NC) ? (cand_enc + ((size_t)b0 * NC + m) * DD)
                       : (clicked_enc + ((size_t)b0 * NH + (m - NC)) * DD);
  float* o1 = (m < NC) ? (cand_enc + ((size_t)(b0 + 1) * NC + m) * DD)
                       : (clicked_enc + ((size_t)(b0 + 1) * NH + (m - NC)) * DD);
  for (int c = tid; c < DD; c += 256) {
    o0[c] = accw[0][c] + accw[1][c];
    o1[c] = accw[2][c] + accw[3][c];
  }
}

// ---------------------------------------------------------------------------
// Fused user logits + attention + click-score dot. Block = one b (50 rows).
// ---------------------------------------------------------------------------
__global__ __launch_bounds__(256) void k_user_attn(
    const __hip_bfloat16* __restrict__ g, const __hip_bfloat16* __restrict__ Bp,
    const float* __restrict__ lin_b, const float* __restrict__ query,
    const float* __restrict__ cand_enc, float* __restrict__ out) {
  __shared__ float lg[64];
  __shared__ float wgt[64];
  __shared__ float accw[4][GSTR];
  __shared__ float uenc[CW];
  __shared__ float wred[4];
  const int b = blockIdx.x, tid = threadIdx.x;
  const int wave = tid >> 6, lane = tid & 63;
  const int quad = lane >> 4, l16 = lane & 15;
  const int rl = wave * 16 + l16;
  const int rclamp = (rl < NH) ? rl : 0;
  const __hip_bfloat16* grow = g + ((size_t)b * NH + rclamp) * GSTR + quad * 8;
  bf16x8 afr[KTILES];
#pragma unroll
  for (int kt = 0; kt < KTILES; ++kt) afr[kt] = *(const bf16x8*)(grow + kt * 32);
  f32x4 acc[NTILES_N];
#pragma unroll
  for (int nt = 0; nt < NTILES_N; ++nt) acc[nt] = (f32x4){0.f, 0.f, 0.f, 0.f};
  for (int kt = 0; kt < KTILES; ++kt) {
    const bf16x8* bp = (const bf16x8*)Bp + (size_t)kt * NTILES_N * 64 + lane;
#pragma unroll
    for (int nt = 0; nt < NTILES_N; ++nt)
      acc[nt] = __builtin_amdgcn_mfma_f32_16x16x32_bf16(afr[kt], bp[nt * 64], acc[nt], 0, 0, 0);
  }
  float part[4] = {0.f, 0.f, 0.f, 0.f};
#pragma unroll
  for (int nt = 0; nt < NTILES_N; ++nt) {
    const int n = nt * 16 + l16;
    const float qv = (n < QQ) ? query[n] : 0.f;
    const float bv = (n < QQ) ? lin_b[n] : 0.f;
#pragma unroll
    for (int r = 0; r < 4; ++r)
      part[r] = fmaf(tanhf(acc[nt][r] + bv), qv, part[r]);
  }
#pragma unroll
  for (int r = 0; r < 4; ++r) {
    float p = part[r];
    p += __shfl_xor(p, 1, 64); p += __shfl_xor(p, 2, 64);
    p += __shfl_xor(p, 4, 64); p += __shfl_xor(p, 8, 64);
    if (l16 == 0) lg[wave * 16 + quad * 4 + r] = p;
  }
  __syncthreads();
  if (tid < 64) {  // softmax over 50 valid rows
    float v = (tid < NH) ? lg[tid] : -3.4e38f;
    float mx = v;
    for (int o = 32; o; o >>= 1) mx = fmaxf(mx, __shfl_xor(mx, o, 64));
    float e = (tid < NH) ? expf(v - mx) : 0.f;
    float sm = e;
    for (int o = 32; o; o >>= 1) sm += __shfl_xor(sm, o, 64);
    wgt[tid] = (tid < NH) ? e / sm : 0.f;
  }
  __syncthreads();
  const float w = (rl < NH) ? wgt[rl] : 0.f;
#pragma unroll
  for (int kt = 0; kt < KTILES; ++kt) {
#pragma unroll
    for (int j = 0; j < 8; ++j) {
      float v = bf2f(afr[kt][j]) * w;
      v += __shfl_xor(v, 1, 64); v += __shfl_xor(v, 2, 64);
      v += __shfl_xor(v, 4, 64); v += __shfl_xor(v, 8, 64);
      if (l16 == 0) accw[wave][kt * 32 + quad * 8 + j] = v;
    }
  }
  __syncthreads();
  for (int c = tid; c < DD; c += 256)
    uenc[c] = accw[0][c] + accw[1][c] + accw[2][c] + accw[3][c];
  __syncthreads();
  for (int c5 = 0; c5 < NC; ++c5) {
    const float* cp = cand_enc + ((size_t)b * NC + c5) * DD;
    float s = 0.f;
    for (int d = tid; d < DD; d += 256) s = fmaf(uenc[d], cp[d], s);
    for (int o = 32; o; o >>= 1) s += __shfl_xor(s, o, 64);
    if (lane == 0) wred[wave] = s;
    __syncthreads();
    if (tid == 0) out[b * NC + c5] = wred[0] + wred[1] + wred[2] + wred[3];
    __syncthreads();
  }
}

// ---------------------------------------------------------------------------
extern "C" void kernel_launch(void* const* d_in, const int* in_sizes, int n_in,
                              void* d_out, int out_size, void* d_ws, size_t ws_size,
                              hipStream_t stream) {
  const int* cand = (const int*)d_in[0];
  const int* clicked = (const int*)d_in[1];
  const float* emb = (const float*)d_in[2];
  const float* news_W = (const float*)d_in[3];
  const float* news_a = (const float*)d_in[4];
  const float* news_lw = (const float*)d_in[5];
  const float* news_lb = (const float*)d_in[6];
  const float* news_q = (const float*)d_in[7];
  const float* user_W = (const float*)d_in[8];
  const float* user_a = (const float*)d_in[9];
  const float* user_lw = (const float*)d_in[10];
  const float* user_lb = (const float*)d_in[11];
  const float* user_q = (const float*)d_in[12];
  float* out = (float*)d_out;

  float* W = (float*)d_ws;
  size_t o = 0;
  auto nxt = [&](size_t n) { size_t c = o; o += (n + 63) & ~(size_t)63; return c; };
  float* EW = W + nxt((size_t)NVOC * DD);
  float* s1v = W + nxt(NVOC);
  float* s2v = W + nxt(NVOC);
  int* perm = (int*)(W + nxt((size_t)NGAT * NROW));
  float* E1 = W + nxt((size_t)NGAT * NROW);
  float* E02 = W + nxt((size_t)NGAT * NROW);
  float* C1 = W + nxt((size_t)NGAT * (NT_NEWS + 1) * CW);
  float* C02 = W + nxt((size_t)NGAT * (NT_NEWS + 1) * CW);
  float* T1N = W + nxt((size_t)NGAT * 8 * CW);
  float* T02N = W + nxt((size_t)NGAT * 8 * CW);
  int* rlistN = (int*)(W + nxt((size_t)NGAT * NROW));
  float* rs1N = W + nxt((size_t)NGAT * NROW);
  int* boffN = (int*)(W + nxt((size_t)NGAT * (NB_NEWS + 2)));
  float* cand_enc = W + nxt((size_t)BN_B * NC * DD);
  float* clicked_enc = W + nxt((size_t)BN_B * NH * DD);
  float* WhU = W + nxt((size_t)NUSR * DD);
  float* s1u = W + nxt(NUSR);
  float* s2u = W + nxt(NUSR);
  int* permU = (int*)(W + nxt(NUSR_PAD));
  float* E1U = W + nxt(NUSR_PAD);
  float* E02U = W + nxt(NUSR_PAD);
  float* C1U = W + nxt((size_t)(NT_USER + 1) * CW);
  float* C02U = W + nxt((size_t)(NT_USER + 1) * CW);
  float* T1U = W + nxt((size_t)13 * CW);
  float* T02U = W + nxt((size_t)13 * CW);
  int* rlistU = (int*)(W + nxt(NUSR));
  float* rs1U = W + nxt(NUSR);
  int* boffU = (int*)(W + nxt(NB_USER + 2));
  __hip_bfloat16* BpN = (__hip_bfloat16*)(W + nxt((size_t)BPELT * 8 / 2));
  __hip_bfloat16* BpU = (__hip_bfloat16*)(W + nxt((size_t)BPELT * 8 / 2));
  __hip_bfloat16* WhiN = (__hip_bfloat16*)(W + nxt((size_t)WPELT * 8 / 2));
  __hip_bfloat16* WloN = (__hip_bfloat16*)(W + nxt((size_t)WPELT * 8 / 2));
  __hip_bfloat16* WhiU = (__hip_bfloat16*)(W + nxt((size_t)WPELT * 8 / 2));
  __hip_bfloat16* WloU = (__hip_bfloat16*)(W + nxt((size_t)WPELT * 8 / 2));
  __hip_bfloat16* g_news = (__hip_bfloat16*)(W + nxt((size_t)NGAT * NROW * GSTR / 2));
  __hip_bfloat16* g_user = (__hip_bfloat16*)(W + nxt((size_t)NUSR * GSTR / 2));

  const int packgrid = (BPELT + 255) / 256;
  const int packWgrid = (WPELT + 255) / 256;

  // 1. packs (news+user in one launch each)
  k_packW<<<dim3(packWgrid, 2), 256, 0, stream>>>(news_W, user_W, WhiN, WloN, WhiU, WloU);
  k_packB<<<dim3(packgrid, 2), 256, 0, stream>>>(news_lw, user_lw, BpN, BpU);
  // 2. EW = emb @ news_W  (+ fused s1/s2)
  k_gemm_mfma<<<(NVOC + 63) / 64, 256, 0, stream>>>(emb, WhiN, WloN, news_a, EW, s1v, s2v, NVOC);
  // 3. sort + exp tables + rank/bucket per news GAT
  k_sort2<<<NGAT, 1024, 0, stream>>>(cand, clicked, s2v, s1v, perm, E1, E02,
                                     rlistN, rs1N, boffN, 0, NROW, NROW, NROW, NB_NEWS);
  // 4. coarse weighted prefix sums (local) + totals
  k_scan<<<dim3(8, NGAT), 320, 0, stream>>>(EW, perm, E1, E02, C1, C02, T1N, T02N,
                                            NROW, NT_NEWS + 1, 8);
  // 5. bucketed GAT rows (inline fix-up) -> g_news
  k_rows2<<<dim3(NB_NEWS + 1, NGAT), 320, 0, stream>>>(EW, perm, E1, E02, C1, C02, T1N, T02N,
                                                       rlistN, rs1N, boffN, g_news,
                                                       NROW, NT_NEWS, NROW, NB_NEWS, 8);
  // 6. fused logits+attention -> cand/clicked encodings
  k_logits_attn<<<NGAT * NROW / 64, 256, 0, stream>>>(g_news, BpN, news_lb, news_q,
                                                      cand_enc, clicked_enc);
  // 7-10. user GAT
  k_gemm_mfma<<<(NUSR + 63) / 64, 256, 0, stream>>>(clicked_enc, WhiU, WloU, user_a,
                                                    WhU, s1u, s2u, NUSR);
  k_sort2<<<1, 1024, 0, stream>>>(nullptr, nullptr, s2u, s1u, permU, E1U, E02U,
                                  rlistU, rs1U, boffU, 1, NUSR, 4096, NUSR_PAD, NB_USER);
  k_scan<<<dim3(13, 1), 320, 0, stream>>>(WhU, permU, E1U, E02U, C1U, C02U, T1U, T02U,
                                          NUSR_PAD, NT_USER + 1, 13);
  k_rows2<<<dim3(NB_USER + 1, 1), 320, 0, stream>>>(WhU, permU, E1U, E02U, C1U, C02U, T1U, T02U,
                                                    rlistU, rs1U, boffU, g_user,
                                                    NUSR, NT_USER, NUSR_PAD, NB_USER, 13);
  // 11. fused user logits + attention + click score
  k_user_attn<<<BN_B, 256, 0, stream>>>(g_user, BpU, user_lb, user_q, cand_enc, out);
}

// Round 8
// 754.289 us; speedup vs baseline: 1.1748x; 1.0323x over previous
//
#include <hip/hip_runtime.h>
#include <hip/hip_bf16.h>

// Problem constants
#define BN_B 64
#define NC 5
#define NH 50
#define NL 32
#define DD 300
#define QQ 200
#define NVOC 50000
#define NGAT 55          // 5 candidate + 50 clicked news GATs
#define NROW 2048        // rows per news GAT (B*L)
#define NUSR 3200        // rows user GAT (B*H)
#define NUSR_PAD 3328    // 13*256
#define CW 304           // prefix array row width (300 data + col300 = denominator)
#define NT_NEWS 128      // 2048/16
#define NT_USER 208      // 3328/16
#define NB_NEWS 128      // max bucket index = NROW/16
#define NB_USER 200      // max bucket index = NUSR/16
#define GSTR 320         // padded g row stride (10 K-tiles of 32 for MFMA)
#define NTILES_N 13      // ceil(200/16)
#define KTILES 10        // 320/32
#define BPELT (NTILES_N * KTILES * 64)  // B-fragment entries (x8 bf16 each)
#define WNT 19
#define WKT 10
#define WPELT (WNT * WKT * 64)
#define KTBYTES (NTILES_N * 64 * 16)    // bytes per kt B-tile = 13312
#define KTCHUNK (KTBYTES / 16)          // 832 16-B chunks

typedef short bf16x8 __attribute__((ext_vector_type(8)));
typedef short bf16x4 __attribute__((ext_vector_type(4)));
typedef float f32x4 __attribute__((ext_vector_type(4)));

static __device__ __forceinline__ float bf2f(short s) {
  return __uint_as_float(((unsigned)(unsigned short)s) << 16);
}

// ---------------------------------------------------------------------------
// Pack W [300,300] fp32 -> split bf16 (hi/lo) B-fragments. y = 0 news, 1 user.
// ---------------------------------------------------------------------------
__global__ __launch_bounds__(256) void k_packW(const float* __restrict__ W0,
                                               const float* __restrict__ W1,
                                               __hip_bfloat16* __restrict__ h0,
                                               __hip_bfloat16* __restrict__ l0,
                                               __hip_bfloat16* __restrict__ h1,
                                               __hip_bfloat16* __restrict__ l1) {
  const float* Wm = blockIdx.y ? W1 : W0;
  __hip_bfloat16* Bhi = blockIdx.y ? h1 : h0;
  __hip_bfloat16* Blo = blockIdx.y ? l1 : l0;
  int e = blockIdx.x * 256 + threadIdx.x;
  if (e >= WPELT) return;
  int lane = e & 63, nt = (e >> 6) % WNT, kt = (e >> 6) / WNT;
  int n = nt * 16 + (lane & 15);
  int k0 = kt * 32 + (lane >> 4) * 8;
  __hip_bfloat16 hv[8], lv[8];
#pragma unroll
  for (int j = 0; j < 8; ++j) {
    int k = k0 + j;
    float v = (k < DD && n < DD) ? Wm[(size_t)k * DD + n] : 0.f;
    __hip_bfloat16 h = __float2bfloat16(v);
    hv[j] = h;
    lv[j] = __float2bfloat16(v - __bfloat162float(h));
  }
  *(bf16x8*)(Bhi + (size_t)e * 8) = *(const bf16x8*)hv;
  *(bf16x8*)(Blo + (size_t)e * 8) = *(const bf16x8*)lv;
}

// Pack lin_w [Q,300] -> bf16 B-fragments, KT-MAJOR: e = (kt*NTILES_N+nt)*64+lane
__global__ __launch_bounds__(256) void k_packB(const float* __restrict__ lw0,
                                               const float* __restrict__ lw1,
                                               __hip_bfloat16* __restrict__ B0,
                                               __hip_bfloat16* __restrict__ B1) {
  const float* lw = blockIdx.y ? lw1 : lw0;
  __hip_bfloat16* Bp = blockIdx.y ? B1 : B0;
  int e = blockIdx.x * 256 + threadIdx.x;
  if (e >= BPELT) return;
  int lane = e & 63, nt = (e >> 6) % NTILES_N, kt = (e >> 6) / NTILES_N;
  int n = nt * 16 + (lane & 15);
  int k0 = kt * 32 + (lane >> 4) * 8;
  __hip_bfloat16 vals[8];
#pragma unroll
  for (int j = 0; j < 8; ++j) {
    int k = k0 + j;
    float v = (n < QQ && k < DD) ? lw[(size_t)n * DD + k] : 0.f;
    vals[j] = __float2bfloat16(v);
  }
  *(bf16x8*)(Bp + (size_t)e * 8) = *(const bf16x8*)vals;
}

// ---------------------------------------------------------------------------
// C[M,300] = A[M,300] @ W[300,300] via split-bf16 MFMA (3 products ~ fp32),
// fused epilogue: s1[row]=C·avec[0:300], s2[row]=C·avec[300:600].
// ---------------------------------------------------------------------------
__global__ __launch_bounds__(256) void k_gemm_mfma(const float* __restrict__ A,
                                                   const __hip_bfloat16* __restrict__ Bhi,
                                                   const __hip_bfloat16* __restrict__ Blo,
                                                   const float* __restrict__ avec,
                                                   float* __restrict__ C,
                                                   float* __restrict__ s1o,
                                                   float* __restrict__ s2o, int M) {
  const int tid = threadIdx.x;
  const int wave = tid >> 6, lane = tid & 63;
  const int quad = lane >> 4, l16 = lane & 15;
  const int rowA = blockIdx.x * 64 + wave * 16 + l16;
  const float* ar = A + (size_t)rowA * DD;
  f32x4 acc[WNT];
#pragma unroll
  for (int nt = 0; nt < WNT; ++nt) acc[nt] = (f32x4){0.f, 0.f, 0.f, 0.f};

  for (int kt = 0; kt < WKT; ++kt) {
    const int k0 = kt * 32 + quad * 8;
    float av[8];
    if (rowA < M && k0 + 8 <= DD) {
      float4 v0 = *(const float4*)(ar + k0);
      float4 v1 = *(const float4*)(ar + k0 + 4);
      av[0] = v0.x; av[1] = v0.y; av[2] = v0.z; av[3] = v0.w;
      av[4] = v1.x; av[5] = v1.y; av[6] = v1.z; av[7] = v1.w;
    } else {
#pragma unroll
      for (int j = 0; j < 8; ++j) {
        int k = k0 + j;
        av[j] = (rowA < M && k < DD) ? ar[k] : 0.f;
      }
    }
    __hip_bfloat16 hv[8], lv[8];
#pragma unroll
    for (int j = 0; j < 8; ++j) {
      __hip_bfloat16 h = __float2bfloat16(av[j]);
      hv[j] = h;
      lv[j] = __float2bfloat16(av[j] - __bfloat162float(h));
    }
    const bf16x8 ah = *(const bf16x8*)hv;
    const bf16x8 al = *(const bf16x8*)lv;
    const bf16x8* bh = (const bf16x8*)Bhi + (size_t)(kt * WNT) * 64 + lane;
    const bf16x8* bl = (const bf16x8*)Blo + (size_t)(kt * WNT) * 64 + lane;
#pragma unroll
    for (int nt = 0; nt < WNT; ++nt) {
      bf16x8 bhf = bh[nt * 64], blf = bl[nt * 64];
      acc[nt] = __builtin_amdgcn_mfma_f32_16x16x32_bf16(ah, bhf, acc[nt], 0, 0, 0);
      acc[nt] = __builtin_amdgcn_mfma_f32_16x16x32_bf16(al, bhf, acc[nt], 0, 0, 0);
      acc[nt] = __builtin_amdgcn_mfma_f32_16x16x32_bf16(ah, blf, acc[nt], 0, 0, 0);
    }
  }
  const int mbase = blockIdx.x * 64 + wave * 16 + quad * 4;
#pragma unroll
  for (int nt = 0; nt < WNT; ++nt) {
    int n = nt * 16 + l16;
    if (n < DD) {
#pragma unroll
      for (int r = 0; r < 4; ++r) {
        int mr = mbase + r;
        if (mr < M) C[(size_t)mr * DD + n] = acc[nt][r];
      }
    }
  }
  // s1/s2 epilogue
  float a1v[WNT], a2v[WNT];
#pragma unroll
  for (int nt = 0; nt < WNT; ++nt) {
    int n = nt * 16 + l16;
    a1v[nt] = (n < DD) ? avec[n] : 0.f;
    a2v[nt] = (n < DD) ? avec[DD + n] : 0.f;
  }
#pragma unroll
  for (int r = 0; r < 4; ++r) {
    float p1 = 0.f, p2 = 0.f;
#pragma unroll
    for (int nt = 0; nt < WNT; ++nt) {
      p1 = fmaf(acc[nt][r], a1v[nt], p1);
      p2 = fmaf(acc[nt][r], a2v[nt], p2);
    }
    p1 += __shfl_xor(p1, 1, 64); p1 += __shfl_xor(p1, 2, 64);
    p1 += __shfl_xor(p1, 4, 64); p1 += __shfl_xor(p1, 8, 64);
    p2 += __shfl_xor(p2, 1, 64); p2 += __shfl_xor(p2, 2, 64);
    p2 += __shfl_xor(p2, 4, 64); p2 += __shfl_xor(p2, 8, 64);
    int mr = mbase + r;
    if (l16 == 0 && mr < M) { s1o[mr] = p1; s2o[mr] = p2; }
  }
}

// ---------------------------------------------------------------------------
// Bitonic sort of s2 + exp tables + rank/bucket epilogue.
// ---------------------------------------------------------------------------
__global__ __launch_bounds__(1024) void k_sort2(const int* __restrict__ cand,
                                                const int* __restrict__ clicked,
                                                const float* __restrict__ s2src,
                                                const float* __restrict__ s1src,
                                                int* __restrict__ perm,
                                                float* __restrict__ E1, float* __restrict__ E02,
                                                int* __restrict__ rlist, float* __restrict__ rs1,
                                                int* __restrict__ boff,
                                                int mode, int N, int SZ, int Epad, int NB) {
  __shared__ float sval[4096];
  __shared__ int spay[4096];
  __shared__ int cnt[224];
  __shared__ int ofs[224];
  const int m = blockIdx.x;
  const int tid = threadIdx.x;
  int* perm_g = perm + (size_t)m * Epad;
  float* E1_g = E1 + (size_t)m * Epad;
  float* E02_g = E02 + (size_t)m * Epad;

  for (int i = tid; i < SZ; i += 1024) {
    float v; int p;
    if (mode == 0) {
      int b = i >> 5, l = i & 31;
      int tok = (m < NC) ? cand[b * (NC * NL) + m * NL + l]
                         : clicked[b * (NH * NL) + (m - NC) * NL + l];
      v = s2src[tok]; p = tok;
    } else {
      if (i < N) { v = s2src[i]; p = i; } else { v = __builtin_inff(); p = 0; }
    }
    sval[i] = v; spay[i] = p;
  }
  __syncthreads();
  for (int k = 2; k <= SZ; k <<= 1) {
    for (int j = k >> 1; j > 0; j >>= 1) {
      for (int i = tid; i < SZ; i += 1024) {
        int ixj = i ^ j;
        if (ixj > i) {
          bool asc = ((i & k) == 0);
          float a = sval[i], bb = sval[ixj];
          bool sw = asc ? (a > bb) : (a < bb);
          if (sw) {
            sval[i] = bb; sval[ixj] = a;
            int t = spay[i]; spay[i] = spay[ixj]; spay[ixj] = t;
          }
        }
      }
      __syncthreads();
    }
  }
  for (int i = tid; i < Epad; i += 1024) {
    E1_g[i] = (i < N) ? expf(sval[i]) : 0.f;
    E02_g[i] = (i < N) ? expf(0.2f * sval[i]) : 0.f;
    perm_g[i] = spay[i];
  }
  __syncthreads();
  for (int t = tid; t <= NB; t += 1024) cnt[t] = 0;
  __syncthreads();
  int* kil = spay;  // reuse (perm already written)
  for (int r = tid; r < N; r += 1024) {
    int tok;
    if (mode == 0) {
      int b = r >> 5, l = r & 31;
      tok = (m < NC) ? cand[b * (NC * NL) + m * NL + l]
                     : clicked[b * (NH * NL) + (m - NC) * NL + l];
    } else tok = r;
    float tau = -s1src[tok];
    int lo = 0, hi = N;
    while (lo < hi) { int mid = (lo + hi) >> 1; if (sval[mid] <= tau) lo = mid + 1; else hi = mid; }
    kil[r] = lo;
    atomicAdd(&cnt[lo >> 4], 1);
  }
  __syncthreads();
  if (tid == 0) {
    int run = 0;
    for (int t = 0; t <= NB; ++t) { ofs[t] = run; run += cnt[t]; cnt[t] = ofs[t]; }
  }
  __syncthreads();
  int* rlist_g = rlist + (size_t)m * N;
  float* rs1_g = rs1 + (size_t)m * N;
  for (int r = tid; r < N; r += 1024) {
    int ki = kil[r];
    int pos = atomicAdd(&cnt[ki >> 4], 1);
    rlist_g[pos] = (ki << 16) | r;
    int tok;
    if (mode == 0) {
      int b = r >> 5, l = r & 31;
      tok = (m < NC) ? cand[b * (NC * NL) + m * NL + l]
                     : clicked[b * (NH * NL) + (m - NC) * NL + l];
    } else tok = r;
    rs1_g[pos] = s1src[tok];
  }
  int* boff_g = boff + (size_t)m * (NB + 2);
  for (int t = tid; t <= NB; t += 1024) boff_g[t] = ofs[t];
  if (tid == 0) boff_g[NB + 1] = N;
}

// ---------------------------------------------------------------------------
// Chunked weighted prefix accumulation (local prefixes) + chunk totals T.
// ---------------------------------------------------------------------------
__global__ __launch_bounds__(320) void k_scan(const float* __restrict__ base,
                                              const int* __restrict__ perm,
                                              const float* __restrict__ E1,
                                              const float* __restrict__ E02,
                                              float* __restrict__ C1, float* __restrict__ C02,
                                              float* __restrict__ T1, float* __restrict__ T02,
                                              int Epad, int cstride, int nkc) {
  const int g = blockIdx.y, kc = blockIdx.x;
  const int col = threadIdx.x;
  const int* perm_g = perm + (size_t)g * Epad;
  const float* E1_g = E1 + (size_t)g * Epad;
  const float* E02_g = E02 + (size_t)g * Epad;
  float* C1_g = C1 + (size_t)g * cstride * CW;
  float* C02_g = C02 + (size_t)g * cstride * CW;
  const bool datacol = (col < DD);
  const float wden = (col == DD) ? 1.f : 0.f;
  float acc1 = 0.f, acc2 = 0.f;
  const int k0 = kc * 256;
#pragma unroll 8
  for (int kk = 0; kk < 256; ++kk) {
    int k = k0 + kk;
    int tok = perm_g[k];
    float e1 = E1_g[k], e02 = E02_g[k];
    float w = datacol ? base[(size_t)tok * DD + col] : wden;
    acc1 = fmaf(e1, w, acc1);
    acc2 = fmaf(e02, w, acc2);
    if ((kk & 15) == 15) {
      int t = (k + 1) >> 4;
      if (col < CW) { C1_g[(size_t)t * CW + col] = acc1; C02_g[(size_t)t * CW + col] = acc2; }
    }
  }
  if (col < CW) {
    T1[((size_t)g * nkc + kc) * CW + col] = acc1;
    T02[((size_t)g * nkc + kc) * CW + col] = acc2;
  }
}

// ---------------------------------------------------------------------------
// Bucketed GAT row construction with inline prefix fix-up.
// ---------------------------------------------------------------------------
__global__ __launch_bounds__(320) void k_rows2(
    const float* __restrict__ base,
    const int* __restrict__ perm, const float* __restrict__ E1, const float* __restrict__ E02,
    const float* __restrict__ C1, const float* __restrict__ C02,
    const float* __restrict__ T1, const float* __restrict__ T02,
    const int* __restrict__ rlist, const float* __restrict__ rs1,
    const int* __restrict__ boff,
    __hip_bfloat16* __restrict__ gout,
    int N, int NT, int Epad, int NB, int nkc) {
  __shared__ float U1[16][CW];
  __shared__ float U02[16][CW];
  __shared__ int tokL[16];
  __shared__ float e1L[16], e02L[16];
  const int t = blockIdx.x, g = blockIdx.y;
  const int col = threadIdx.x;
  const int* boff_g = boff + (size_t)g * (NB + 2);
  const int i0 = boff_g[t], i1 = boff_g[t + 1];
  if (i0 >= i1) return;
  const int* perm_g = perm + (size_t)g * Epad;
  const float* E1_g = E1 + (size_t)g * Epad;
  const float* E02_g = E02 + (size_t)g * Epad;
  if (col < 16) {
    int idx = t * 16 + col;
    bool v = idx < N;
    tokL[col] = v ? perm_g[idx] : 0;
    e1L[col] = v ? E1_g[idx] : 0.f;
    e02L[col] = v ? E02_g[idx] : 0.f;
  }
  __syncthreads();
  if (col < CW) {
    const int kc = (t == 0) ? 0 : ((t - 1) >> 4);
    float tot1 = 0.f, pre1 = 0.f, pre02 = 0.f;
    for (int c = 0; c < nkc; ++c) {
      float tv = T1[((size_t)g * nkc + c) * CW + col];
      tot1 += tv;
      if (c < kc) pre1 += tv;
    }
    for (int c = 0; c < kc; ++c) pre02 += T02[((size_t)g * nkc + c) * CW + col];
    if (t > 0) {
      pre1 += C1[((size_t)g * (NT + 1) + t) * CW + col];
      pre02 += C02[((size_t)g * (NT + 1) + t) * CW + col];
    }
    float u1 = tot1 - pre1;
    float u02 = pre02;
    float wv[16];
#pragma unroll
    for (int j = 0; j < 16; ++j) {
      if (col < DD) wv[j] = ((t * 16 + j) < N) ? base[(size_t)tokL[j] * DD + col] : 0.f;
      else wv[j] = (col == DD) ? 1.f : 0.f;
    }
#pragma unroll
    for (int j = 0; j < 16; ++j) {
      U1[j][col] = u1; U02[j][col] = u02;
      u1 = fmaf(-e1L[j], wv[j], u1);
      u02 = fmaf(e02L[j], wv[j], u02);
    }
  }
  __syncthreads();
  const int slot = col / 80, cp = col % 80;
  const int c0 = cp * 4;
  const int* rlist_g = rlist + (size_t)g * N;
  const float* rs1_g = rs1 + (size_t)g * N;
  for (int i = i0 + slot; i < i1; i += 4) {
    int e = rlist_g[i];
    int r = e & 0xffff, nr = (e >> 16) & 15;
    float s1 = rs1_g[i];
    float es1 = expf(s1), es02 = expf(0.2f * s1);
    float den = es1 * U1[nr][DD] + es02 * U02[nr][DD];
    float rden = 1.f / den;
    short ov[4];
#pragma unroll
    for (int q = 0; q < 4; ++q) {
      int c = c0 + q;
      float ev = 0.f;
      if (c < DD) {
        float num = es1 * U1[nr][c] + es02 * U02[nr][c];
        float gg = num * rden;
        ev = (gg > 0.f) ? gg : expm1f(gg);
      }
      __hip_bfloat16 h = __float2bfloat16(ev);
      ov[q] = *(short*)&h;
    }
    *(bf16x4*)(gout + ((size_t)g * N + r) * GSTR + c0) = *(bf16x4*)ov;
  }
}

// ---------------------------------------------------------------------------
// Fused news logits + additive attention, LDS-STAGED B (canonical GEMM form).
// Block = 512 threads (8 waves) = 128 rows = 4 (b,m) groups.
// B tile for each kt (13.3 KB) double-buffered in LDS; staged via registers
// (load kt+2 -> regs overlaps compute of kt). 8 waves share each tile.
// ---------------------------------------------------------------------------
__global__ __launch_bounds__(512) void k_logits_attn(
    const __hip_bfloat16* __restrict__ g, const __hip_bfloat16* __restrict__ Bp,
    const float* __restrict__ lin_b, const float* __restrict__ query,
    float* __restrict__ cand_enc, float* __restrict__ clicked_enc) {
  __shared__ __align__(16) short Bs[2][NTILES_N * 512];  // 2 x 13312 B
  __shared__ float lg[128];
  __shared__ float wgt[128];
  __shared__ float accw[8][GSTR];
  const int tid = threadIdx.x;
  const int wave = tid >> 6, lane = tid & 63;
  const int quad = lane >> 4, l16 = lane & 15;
  const int m = blockIdx.x >> 4;             // 16 blocks per gat
  const int rbase = (blockIdx.x & 15) * 128; // row within gat
  // A fragments: 10 kt x 16B per lane
  const __hip_bfloat16* grow =
      g + ((size_t)m * NROW + rbase + wave * 16 + l16) * GSTR + quad * 8;
  bf16x8 afr[KTILES];
#pragma unroll
  for (int kt = 0; kt < KTILES; ++kt) afr[kt] = *(const bf16x8*)(grow + kt * 32);

  // ---- staged K-loop ----
  const float4* bsrc = (const float4*)Bp;       // 16-B chunks, kt-major
  float4* bdst0 = (float4*)&Bs[0][0];
  float4* bdst1 = (float4*)&Bs[1][0];
  // preload kt0 -> regs -> LDS buf0; issue kt1 -> regs
  float4 st0, st1;
  {
    st0 = bsrc[tid];
    if (tid < KTCHUNK - 512) st1 = bsrc[512 + tid];
    bdst0[tid] = st0;
    if (tid < KTCHUNK - 512) bdst0[512 + tid] = st1;
    st0 = bsrc[KTCHUNK + tid];
    if (tid < KTCHUNK - 512) st1 = bsrc[KTCHUNK + 512 + tid];
  }
  __syncthreads();
  f32x4 acc[NTILES_N];
#pragma unroll
  for (int nt = 0; nt < NTILES_N; ++nt) acc[nt] = (f32x4){0.f, 0.f, 0.f, 0.f};
  int c = 0;
  for (int kt = 0; kt < KTILES; ++kt) {
    const bf16x8* bp = (const bf16x8*)&Bs[c][0] + lane;
#pragma unroll
    for (int nt = 0; nt < NTILES_N; ++nt)
      acc[nt] = __builtin_amdgcn_mfma_f32_16x16x32_bf16(afr[kt], bp[nt * 64], acc[nt], 0, 0, 0);
    if (kt < KTILES - 1) {
      __syncthreads();  // everyone done reading buf 1-c (from kt-1)
      float4* bd = c ? bdst0 : bdst1;
      bd[tid] = st0;
      if (tid < KTCHUNK - 512) bd[512 + tid] = st1;
      if (kt < KTILES - 2) {
        st0 = bsrc[(size_t)(kt + 2) * KTCHUNK + tid];
        if (tid < KTCHUNK - 512) st1 = bsrc[(size_t)(kt + 2) * KTCHUNK + 512 + tid];
      }
      __syncthreads();  // buf 1-c ready
      c ^= 1;
    }
  }
  // ---- epilogue: tanh + query dot -> per-row logits ----
  float part[4] = {0.f, 0.f, 0.f, 0.f};
#pragma unroll
  for (int nt = 0; nt < NTILES_N; ++nt) {
    const int n = nt * 16 + l16;
    const float qv = (n < QQ) ? query[n] : 0.f;
    const float bv = (n < QQ) ? lin_b[n] : 0.f;
#pragma unroll
    for (int r = 0; r < 4; ++r)
      part[r] = fmaf(tanhf(acc[nt][r] + bv), qv, part[r]);
  }
#pragma unroll
  for (int r = 0; r < 4; ++r) {
    float p = part[r];
    p += __shfl_xor(p, 1, 64); p += __shfl_xor(p, 2, 64);
    p += __shfl_xor(p, 4, 64); p += __shfl_xor(p, 8, 64);
    if (l16 == 0) lg[wave * 16 + quad * 4 + r] = p;
  }
  __syncthreads();
  if (tid < 128) {  // softmax per 32-row group (xor<=16 stays within group)
    float v = lg[tid];
    float mx = v;
    mx = fmaxf(mx, __shfl_xor(mx, 1, 64)); mx = fmaxf(mx, __shfl_xor(mx, 2, 64));
    mx = fmaxf(mx, __shfl_xor(mx, 4, 64)); mx = fmaxf(mx, __shfl_xor(mx, 8, 64));
    mx = fmaxf(mx, __shfl_xor(mx, 16, 64));
    float e = expf(v - mx), sm = e;
    sm += __shfl_xor(sm, 1, 64); sm += __shfl_xor(sm, 2, 64);
    sm += __shfl_xor(sm, 4, 64); sm += __shfl_xor(sm, 8, 64);
    sm += __shfl_xor(sm, 16, 64);
    wgt[tid] = e / sm;
  }
  __syncthreads();
  const float w = wgt[wave * 16 + l16];
#pragma unroll
  for (int kt = 0; kt < KTILES; ++kt) {
#pragma unroll
    for (int j = 0; j < 8; ++j) {
      float v = bf2f(afr[kt][j]) * w;
      v += __shfl_xor(v, 1, 64); v += __shfl_xor(v, 2, 64);
      v += __shfl_xor(v, 4, 64); v += __shfl_xor(v, 8, 64);
      if (l16 == 0) accw[wave][kt * 32 + quad * 8 + j] = v;
    }
  }
  __syncthreads();
  const int b0 = rbase >> 5;
  for (int idx = tid; idx < 4 * DD; idx += 512) {
    int j = idx / DD, cc = idx % DD;
    float* op = (m < NC) ? (cand_enc + ((size_t)(b0 + j) * NC + m) * DD)
                         : (clicked_enc + ((size_t)(b0 + j) * NH + (m - NC)) * DD);
    op[cc] = accw[2 * j][cc] + accw[2 * j + 1][cc];
  }
}

// ---------------------------------------------------------------------------
// Fused user logits + attention + click-score dot. Block = one b (50 rows).
// ---------------------------------------------------------------------------
__global__ __launch_bounds__(256) void k_user_attn(
    const __hip_bfloat16* __restrict__ g, const __hip_bfloat16* __restrict__ Bp,
    const float* __restrict__ lin_b, const float* __restrict__ query,
    const float* __restrict__ cand_enc, float* __restrict__ out) {
  __shared__ float lg[64];
  __shared__ float wgt[64];
  __shared__ float accw[4][GSTR];
  __shared__ float uenc[CW];
  __shared__ float wred[4];
  const int b = blockIdx.x, tid = threadIdx.x;
  const int wave = tid >> 6, lane = tid & 63;
  const int quad = lane >> 4, l16 = lane & 15;
  const int rl = wave * 16 + l16;
  const int rclamp = (rl < NH) ? rl : 0;
  const __hip_bfloat16* grow = g + ((size_t)b * NH + rclamp) * GSTR + quad * 8;
  bf16x8 afr[KTILES];
#pragma unroll
  for (int kt = 0; kt < KTILES; ++kt) afr[kt] = *(const bf16x8*)(grow + kt * 32);
  f32x4 acc[NTILES_N];
#pragma unroll
  for (int nt = 0; nt < NTILES_N; ++nt) acc[nt] = (f32x4){0.f, 0.f, 0.f, 0.f};
  for (int kt = 0; kt < KTILES; ++kt) {
    const bf16x8* bp = (const bf16x8*)Bp + (size_t)kt * NTILES_N * 64 + lane;
#pragma unroll
    for (int nt = 0; nt < NTILES_N; ++nt)
      acc[nt] = __builtin_amdgcn_mfma_f32_16x16x32_bf16(afr[kt], bp[nt * 64], acc[nt], 0, 0, 0);
  }
  float part[4] = {0.f, 0.f, 0.f, 0.f};
#pragma unroll
  for (int nt = 0; nt < NTILES_N; ++nt) {
    const int n = nt * 16 + l16;
    const float qv = (n < QQ) ? query[n] : 0.f;
    const float bv = (n < QQ) ? lin_b[n] : 0.f;
#pragma unroll
    for (int r = 0; r < 4; ++r)
      part[r] = fmaf(tanhf(acc[nt][r] + bv), qv, part[r]);
  }
#pragma unroll
  for (int r = 0; r < 4; ++r) {
    float p = part[r];
    p += __shfl_xor(p, 1, 64); p += __shfl_xor(p, 2, 64);
    p += __shfl_xor(p, 4, 64); p += __shfl_xor(p, 8, 64);
    if (l16 == 0) lg[wave * 16 + quad * 4 + r] = p;
  }
  __syncthreads();
  if (tid < 64) {  // softmax over 50 valid rows
    float v = (tid < NH) ? lg[tid] : -3.4e38f;
    float mx = v;
    for (int o = 32; o; o >>= 1) mx = fmaxf(mx, __shfl_xor(mx, o, 64));
    float e = (tid < NH) ? expf(v - mx) : 0.f;
    float sm = e;
    for (int o = 32; o; o >>= 1) sm += __shfl_xor(sm, o, 64);
    wgt[tid] = (tid < NH) ? e / sm : 0.f;
  }
  __syncthreads();
  const float w = (rl < NH) ? wgt[rl] : 0.f;
#pragma unroll
  for (int kt = 0; kt < KTILES; ++kt) {
#pragma unroll
    for (int j = 0; j < 8; ++j) {
      float v = bf2f(afr[kt][j]) * w;
      v += __shfl_xor(v, 1, 64); v += __shfl_xor(v, 2, 64);
      v += __shfl_xor(v, 4, 64); v += __shfl_xor(v, 8, 64);
      if (l16 == 0) accw[wave][kt * 32 + quad * 8 + j] = v;
    }
  }
  __syncthreads();
  for (int c = tid; c < DD; c += 256)
    uenc[c] = accw[0][c] + accw[1][c] + accw[2][c] + accw[3][c];
  __syncthreads();
  for (int c5 = 0; c5 < NC; ++c5) {
    const float* cp = cand_enc + ((size_t)b * NC + c5) * DD;
    float s = 0.f;
    for (int d = tid; d < DD; d += 256) s = fmaf(uenc[d], cp[d], s);
    for (int o = 32; o; o >>= 1) s += __shfl_xor(s, o, 64);
    if (lane == 0) wred[wave] = s;
    __syncthreads();
    if (tid == 0) out[b * NC + c5] = wred[0] + wred[1] + wred[2] + wred[3];
    __syncthreads();
  }
}

// ---------------------------------------------------------------------------
extern "C" void kernel_launch(void* const* d_in, const int* in_sizes, int n_in,
                              void* d_out, int out_size, void* d_ws, size_t ws_size,
                              hipStream_t stream) {
  const int* cand = (const int*)d_in[0];
  const int* clicked = (const int*)d_in[1];
  const float* emb = (const float*)d_in[2];
  const float* news_W = (const float*)d_in[3];
  const float* news_a = (const float*)d_in[4];
  const float* news_lw = (const float*)d_in[5];
  const float* news_lb = (const float*)d_in[6];
  const float* news_q = (const float*)d_in[7];
  const float* user_W = (const float*)d_in[8];
  const float* user_a = (const float*)d_in[9];
  const float* user_lw = (const float*)d_in[10];
  const float* user_lb = (const float*)d_in[11];
  const float* user_q = (const float*)d_in[12];
  float* out = (float*)d_out;

  float* W = (float*)d_ws;
  size_t o = 0;
  auto nxt = [&](size_t n) { size_t c = o; o += (n + 63) & ~(size_t)63; return c; };
  float* EW = W + nxt((size_t)NVOC * DD);
  float* s1v = W + nxt(NVOC);
  float* s2v = W + nxt(NVOC);
  int* perm = (int*)(W + nxt((size_t)NGAT * NROW));
  float* E1 = W + nxt((size_t)NGAT * NROW);
  float* E02 = W + nxt((size_t)NGAT * NROW);
  float* C1 = W + nxt((size_t)NGAT * (NT_NEWS + 1) * CW);
  float* C02 = W + nxt((size_t)NGAT * (NT_NEWS + 1) * CW);
  float* T1N = W + nxt((size_t)NGAT * 8 * CW);
  float* T02N = W + nxt((size_t)NGAT * 8 * CW);
  int* rlistN = (int*)(W + nxt((size_t)NGAT * NROW));
  float* rs1N = W + nxt((size_t)NGAT * NROW);
  int* boffN = (int*)(W + nxt((size_t)NGAT * (NB_NEWS + 2)));
  float* cand_enc = W + nxt((size_t)BN_B * NC * DD);
  float* clicked_enc = W + nxt((size_t)BN_B * NH * DD);
  float* WhU = W + nxt((size_t)NUSR * DD);
  float* s1u = W + nxt(NUSR);
  float* s2u = W + nxt(NUSR);
  int* permU = (int*)(W + nxt(NUSR_PAD));
  float* E1U = W + nxt(NUSR_PAD);
  float* E02U = W + nxt(NUSR_PAD);
  float* C1U = W + nxt((size_t)(NT_USER + 1) * CW);
  float* C02U = W + nxt((size_t)(NT_USER + 1) * CW);
  float* T1U = W + nxt((size_t)13 * CW);
  float* T02U = W + nxt((size_t)13 * CW);
  int* rlistU = (int*)(W + nxt(NUSR));
  float* rs1U = W + nxt(NUSR);
  int* boffU = (int*)(W + nxt(NB_USER + 2));
  __hip_bfloat16* BpN = (__hip_bfloat16*)(W + nxt((size_t)BPELT * 8 / 2));
  __hip_bfloat16* BpU = (__hip_bfloat16*)(W + nxt((size_t)BPELT * 8 / 2));
  __hip_bfloat16* WhiN = (__hip_bfloat16*)(W + nxt((size_t)WPELT * 8 / 2));
  __hip_bfloat16* WloN = (__hip_bfloat16*)(W + nxt((size_t)WPELT * 8 / 2));
  __hip_bfloat16* WhiU = (__hip_bfloat16*)(W + nxt((size_t)WPELT * 8 / 2));
  __hip_bfloat16* WloU = (__hip_bfloat16*)(W + nxt((size_t)WPELT * 8 / 2));
  __hip_bfloat16* g_news = (__hip_bfloat16*)(W + nxt((size_t)NGAT * NROW * GSTR / 2));
  __hip_bfloat16* g_user = (__hip_bfloat16*)(W + nxt((size_t)NUSR * GSTR / 2));

  const int packgrid = (BPELT + 255) / 256;
  const int packWgrid = (WPELT + 255) / 256;

  // 1. packs (news+user in one launch each)
  k_packW<<<dim3(packWgrid, 2), 256, 0, stream>>>(news_W, user_W, WhiN, WloN, WhiU, WloU);
  k_packB<<<dim3(packgrid, 2), 256, 0, stream>>>(news_lw, user_lw, BpN, BpU);
  // 2. EW = emb @ news_W  (+ fused s1/s2)
  k_gemm_mfma<<<(NVOC + 63) / 64, 256, 0, stream>>>(emb, WhiN, WloN, news_a, EW, s1v, s2v, NVOC);
  // 3. sort + exp tables + rank/bucket per news GAT
  k_sort2<<<NGAT, 1024, 0, stream>>>(cand, clicked, s2v, s1v, perm, E1, E02,
                                     rlistN, rs1N, boffN, 0, NROW, NROW, NROW, NB_NEWS);
  // 4. coarse weighted prefix sums (local) + totals
  k_scan<<<dim3(8, NGAT), 320, 0, stream>>>(EW, perm, E1, E02, C1, C02, T1N, T02N,
                                            NROW, NT_NEWS + 1, 8);
  // 5. bucketed GAT rows (inline fix-up) -> g_news
  k_rows2<<<dim3(NB_NEWS + 1, NGAT), 320, 0, stream>>>(EW, perm, E1, E02, C1, C02, T1N, T02N,
                                                       rlistN, rs1N, boffN, g_news,
                                                       NROW, NT_NEWS, NROW, NB_NEWS, 8);
  // 6. fused logits+attention (LDS-staged GEMM) -> cand/clicked encodings
  k_logits_attn<<<NGAT * NROW / 128, 512, 0, stream>>>(g_news, BpN, news_lb, news_q,
                                                       cand_enc, clicked_enc);
  // 7-10. user GAT
  k_gemm_mfma<<<(NUSR + 63) / 64, 256, 0, stream>>>(clicked_enc, WhiU, WloU, user_a,
                                                    WhU, s1u, s2u, NUSR);
  k_sort2<<<1, 1024, 0, stream>>>(nullptr, nullptr, s2u, s1u, permU, E1U, E02U,
                                  rlistU, rs1U, boffU, 1, NUSR, 4096, NUSR_PAD, NB_USER);
  k_scan<<<dim3(13, 1), 320, 0, stream>>>(WhU, permU, E1U, E02U, C1U, C02U, T1U, T02U,
                                          NUSR_PAD, NT_USER + 1, 13);
  k_rows2<<<dim3(NB_USER + 1, 1), 320, 0, stream>>>(WhU, permU, E1U, E02U, C1U, C02U, T1U, T02U,
                                                    rlistU, rs1U, boffU, g_user,
                                                    NUSR, NT_USER, NUSR_PAD, NB_USER, 13);
  // 11. fused user logits + attention + click score
  k_user_attn<<<BN_B, 256, 0, stream>>>(g_user, BpU, user_lb, user_q, cand_enc, out);
}

// Round 9
// 745.405 us; speedup vs baseline: 1.1888x; 1.0119x over previous
//
#include <hip/hip_runtime.h>
#include <hip/hip_bf16.h>

// Problem constants
#define BN_B 64
#define NC 5
#define NH 50
#define NL 32
#define DD 300
#define QQ 200
#define NVOC 50000
#define NGAT 55          // 5 candidate + 50 clicked news GATs
#define NROW 2048        // rows per news GAT (B*L)
#define NUSR 3200        // rows user GAT (B*H)
#define NUSR_PAD 3328    // 13*256
#define CW 304           // prefix array row width (300 data + col300 = denominator)
#define NT_NEWS 128      // 2048/16
#define NT_USER 208      // 3328/16
#define NB_NEWS 128      // max bucket index = NROW/16
#define NB_USER 200      // max bucket index = NUSR/16
#define GSTR 320         // padded g row stride (10 K-tiles of 32 for MFMA)
#define NTILES_N 13      // ceil(200/16)
#define KTILES 10        // 320/32
#define BPELT (NTILES_N * KTILES * 64)  // B-fragment entries (x8 bf16 each)
#define WNT 19
#define WKT 10
#define WPELT (WNT * WKT * 64)
#define KTBYTES (NTILES_N * 64 * 16)    // bytes per kt B-tile = 13312
#define KTCHUNK (KTBYTES / 16)          // 832 16-B chunks

typedef short bf16x8 __attribute__((ext_vector_type(8)));
typedef short bf16x4 __attribute__((ext_vector_type(4)));
typedef float f32x4 __attribute__((ext_vector_type(4)));

static __device__ __forceinline__ float bf2f(short s) {
  return __uint_as_float(((unsigned)(unsigned short)s) << 16);
}

// ---------------------------------------------------------------------------
// Pack W [300,300] fp32 -> split bf16 (hi/lo) B-fragments. y = 0 news, 1 user.
// ---------------------------------------------------------------------------
__global__ __launch_bounds__(256) void k_packW(const float* __restrict__ W0,
                                               const float* __restrict__ W1,
                                               __hip_bfloat16* __restrict__ h0,
                                               __hip_bfloat16* __restrict__ l0,
                                               __hip_bfloat16* __restrict__ h1,
                                               __hip_bfloat16* __restrict__ l1) {
  const float* Wm = blockIdx.y ? W1 : W0;
  __hip_bfloat16* Bhi = blockIdx.y ? h1 : h0;
  __hip_bfloat16* Blo = blockIdx.y ? l1 : l0;
  int e = blockIdx.x * 256 + threadIdx.x;
  if (e >= WPELT) return;
  int lane = e & 63, nt = (e >> 6) % WNT, kt = (e >> 6) / WNT;
  int n = nt * 16 + (lane & 15);
  int k0 = kt * 32 + (lane >> 4) * 8;
  __hip_bfloat16 hv[8], lv[8];
#pragma unroll
  for (int j = 0; j < 8; ++j) {
    int k = k0 + j;
    float v = (k < DD && n < DD) ? Wm[(size_t)k * DD + n] : 0.f;
    __hip_bfloat16 h = __float2bfloat16(v);
    hv[j] = h;
    lv[j] = __float2bfloat16(v - __bfloat162float(h));
  }
  *(bf16x8*)(Bhi + (size_t)e * 8) = *(const bf16x8*)hv;
  *(bf16x8*)(Blo + (size_t)e * 8) = *(const bf16x8*)lv;
}

// Pack lin_w [Q,300] -> bf16 B-fragments, KT-MAJOR: e = (kt*NTILES_N+nt)*64+lane
__global__ __launch_bounds__(256) void k_packB(const float* __restrict__ lw0,
                                               const float* __restrict__ lw1,
                                               __hip_bfloat16* __restrict__ B0,
                                               __hip_bfloat16* __restrict__ B1) {
  const float* lw = blockIdx.y ? lw1 : lw0;
  __hip_bfloat16* Bp = blockIdx.y ? B1 : B0;
  int e = blockIdx.x * 256 + threadIdx.x;
  if (e >= BPELT) return;
  int lane = e & 63, nt = (e >> 6) % NTILES_N, kt = (e >> 6) / NTILES_N;
  int n = nt * 16 + (lane & 15);
  int k0 = kt * 32 + (lane >> 4) * 8;
  __hip_bfloat16 vals[8];
#pragma unroll
  for (int j = 0; j < 8; ++j) {
    int k = k0 + j;
    float v = (n < QQ && k < DD) ? lw[(size_t)n * DD + k] : 0.f;
    vals[j] = __float2bfloat16(v);
  }
  *(bf16x8*)(Bp + (size_t)e * 8) = *(const bf16x8*)vals;
}

// ---------------------------------------------------------------------------
// C[M,300] = A[M,300] @ W[300,300] via split-bf16 MFMA (3 products ~ fp32),
// fused epilogue: s1[row]=C·avec[0:300], s2[row]=C·avec[300:600].
// ---------------------------------------------------------------------------
__global__ __launch_bounds__(256) void k_gemm_mfma(const float* __restrict__ A,
                                                   const __hip_bfloat16* __restrict__ Bhi,
                                                   const __hip_bfloat16* __restrict__ Blo,
                                                   const float* __restrict__ avec,
                                                   float* __restrict__ C,
                                                   float* __restrict__ s1o,
                                                   float* __restrict__ s2o, int M) {
  const int tid = threadIdx.x;
  const int wave = tid >> 6, lane = tid & 63;
  const int quad = lane >> 4, l16 = lane & 15;
  const int rowA = blockIdx.x * 64 + wave * 16 + l16;
  const float* ar = A + (size_t)rowA * DD;
  f32x4 acc[WNT];
#pragma unroll
  for (int nt = 0; nt < WNT; ++nt) acc[nt] = (f32x4){0.f, 0.f, 0.f, 0.f};

  for (int kt = 0; kt < WKT; ++kt) {
    const int k0 = kt * 32 + quad * 8;
    float av[8];
    if (rowA < M && k0 + 8 <= DD) {
      float4 v0 = *(const float4*)(ar + k0);
      float4 v1 = *(const float4*)(ar + k0 + 4);
      av[0] = v0.x; av[1] = v0.y; av[2] = v0.z; av[3] = v0.w;
      av[4] = v1.x; av[5] = v1.y; av[6] = v1.z; av[7] = v1.w;
    } else {
#pragma unroll
      for (int j = 0; j < 8; ++j) {
        int k = k0 + j;
        av[j] = (rowA < M && k < DD) ? ar[k] : 0.f;
      }
    }
    __hip_bfloat16 hv[8], lv[8];
#pragma unroll
    for (int j = 0; j < 8; ++j) {
      __hip_bfloat16 h = __float2bfloat16(av[j]);
      hv[j] = h;
      lv[j] = __float2bfloat16(av[j] - __bfloat162float(h));
    }
    const bf16x8 ah = *(const bf16x8*)hv;
    const bf16x8 al = *(const bf16x8*)lv;
    const bf16x8* bh = (const bf16x8*)Bhi + (size_t)(kt * WNT) * 64 + lane;
    const bf16x8* bl = (const bf16x8*)Blo + (size_t)(kt * WNT) * 64 + lane;
#pragma unroll
    for (int nt = 0; nt < WNT; ++nt) {
      bf16x8 bhf = bh[nt * 64], blf = bl[nt * 64];
      acc[nt] = __builtin_amdgcn_mfma_f32_16x16x32_bf16(ah, bhf, acc[nt], 0, 0, 0);
      acc[nt] = __builtin_amdgcn_mfma_f32_16x16x32_bf16(al, bhf, acc[nt], 0, 0, 0);
      acc[nt] = __builtin_amdgcn_mfma_f32_16x16x32_bf16(ah, blf, acc[nt], 0, 0, 0);
    }
  }
  const int mbase = blockIdx.x * 64 + wave * 16 + quad * 4;
#pragma unroll
  for (int nt = 0; nt < WNT; ++nt) {
    int n = nt * 16 + l16;
    if (n < DD) {
#pragma unroll
      for (int r = 0; r < 4; ++r) {
        int mr = mbase + r;
        if (mr < M) C[(size_t)mr * DD + n] = acc[nt][r];
      }
    }
  }
  // s1/s2 epilogue
  float a1v[WNT], a2v[WNT];
#pragma unroll
  for (int nt = 0; nt < WNT; ++nt) {
    int n = nt * 16 + l16;
    a1v[nt] = (n < DD) ? avec[n] : 0.f;
    a2v[nt] = (n < DD) ? avec[DD + n] : 0.f;
  }
#pragma unroll
  for (int r = 0; r < 4; ++r) {
    float p1 = 0.f, p2 = 0.f;
#pragma unroll
    for (int nt = 0; nt < WNT; ++nt) {
      p1 = fmaf(acc[nt][r], a1v[nt], p1);
      p2 = fmaf(acc[nt][r], a2v[nt], p2);
    }
    p1 += __shfl_xor(p1, 1, 64); p1 += __shfl_xor(p1, 2, 64);
    p1 += __shfl_xor(p1, 4, 64); p1 += __shfl_xor(p1, 8, 64);
    p2 += __shfl_xor(p2, 1, 64); p2 += __shfl_xor(p2, 2, 64);
    p2 += __shfl_xor(p2, 4, 64); p2 += __shfl_xor(p2, 8, 64);
    int mr = mbase + r;
    if (l16 == 0 && mr < M) { s1o[mr] = p1; s2o[mr] = p2; }
  }
}

// ---------------------------------------------------------------------------
// Bitonic sort of s2 + exp tables + rank/bucket epilogue.
// ---------------------------------------------------------------------------
__global__ __launch_bounds__(1024) void k_sort2(const int* __restrict__ cand,
                                                const int* __restrict__ clicked,
                                                const float* __restrict__ s2src,
                                                const float* __restrict__ s1src,
                                                int* __restrict__ perm,
                                                float* __restrict__ E1, float* __restrict__ E02,
                                                int* __restrict__ rlist, float* __restrict__ rs1,
                                                int* __restrict__ boff,
                                                int mode, int N, int SZ, int Epad, int NB) {
  __shared__ float sval[4096];
  __shared__ int spay[4096];
  __shared__ int cnt[224];
  __shared__ int ofs[224];
  const int m = blockIdx.x;
  const int tid = threadIdx.x;
  int* perm_g = perm + (size_t)m * Epad;
  float* E1_g = E1 + (size_t)m * Epad;
  float* E02_g = E02 + (size_t)m * Epad;

  for (int i = tid; i < SZ; i += 1024) {
    float v; int p;
    if (mode == 0) {
      int b = i >> 5, l = i & 31;
      int tok = (m < NC) ? cand[b * (NC * NL) + m * NL + l]
                         : clicked[b * (NH * NL) + (m - NC) * NL + l];
      v = s2src[tok]; p = tok;
    } else {
      if (i < N) { v = s2src[i]; p = i; } else { v = __builtin_inff(); p = 0; }
    }
    sval[i] = v; spay[i] = p;
  }
  __syncthreads();
  for (int k = 2; k <= SZ; k <<= 1) {
    for (int j = k >> 1; j > 0; j >>= 1) {
      for (int i = tid; i < SZ; i += 1024) {
        int ixj = i ^ j;
        if (ixj > i) {
          bool asc = ((i & k) == 0);
          float a = sval[i], bb = sval[ixj];
          bool sw = asc ? (a > bb) : (a < bb);
          if (sw) {
            sval[i] = bb; sval[ixj] = a;
            int t = spay[i]; spay[i] = spay[ixj]; spay[ixj] = t;
          }
        }
      }
      __syncthreads();
    }
  }
  for (int i = tid; i < Epad; i += 1024) {
    E1_g[i] = (i < N) ? expf(sval[i]) : 0.f;
    E02_g[i] = (i < N) ? expf(0.2f * sval[i]) : 0.f;
    perm_g[i] = spay[i];
  }
  __syncthreads();
  for (int t = tid; t <= NB; t += 1024) cnt[t] = 0;
  __syncthreads();
  int* kil = spay;  // reuse (perm already written)
  for (int r = tid; r < N; r += 1024) {
    int tok;
    if (mode == 0) {
      int b = r >> 5, l = r & 31;
      tok = (m < NC) ? cand[b * (NC * NL) + m * NL + l]
                     : clicked[b * (NH * NL) + (m - NC) * NL + l];
    } else tok = r;
    float tau = -s1src[tok];
    int lo = 0, hi = N;
    while (lo < hi) { int mid = (lo + hi) >> 1; if (sval[mid] <= tau) lo = mid + 1; else hi = mid; }
    kil[r] = lo;
    atomicAdd(&cnt[lo >> 4], 1);
  }
  __syncthreads();
  if (tid == 0) {
    int run = 0;
    for (int t = 0; t <= NB; ++t) { ofs[t] = run; run += cnt[t]; cnt[t] = ofs[t]; }
  }
  __syncthreads();
  int* rlist_g = rlist + (size_t)m * N;
  float* rs1_g = rs1 + (size_t)m * N;
  for (int r = tid; r < N; r += 1024) {
    int ki = kil[r];
    int pos = atomicAdd(&cnt[ki >> 4], 1);
    rlist_g[pos] = (ki << 16) | r;
    int tok;
    if (mode == 0) {
      int b = r >> 5, l = r & 31;
      tok = (m < NC) ? cand[b * (NC * NL) + m * NL + l]
                     : clicked[b * (NH * NL) + (m - NC) * NL + l];
    } else tok = r;
    rs1_g[pos] = s1src[tok];
  }
  int* boff_g = boff + (size_t)m * (NB + 2);
  for (int t = tid; t <= NB; t += 1024) boff_g[t] = ofs[t];
  if (tid == 0) boff_g[NB + 1] = N;
}

// ---------------------------------------------------------------------------
// Chunked weighted prefix accumulation (local prefixes) + chunk totals T.
// ---------------------------------------------------------------------------
__global__ __launch_bounds__(320) void k_scan(const float* __restrict__ base,
                                              const int* __restrict__ perm,
                                              const float* __restrict__ E1,
                                              const float* __restrict__ E02,
                                              float* __restrict__ C1, float* __restrict__ C02,
                                              float* __restrict__ T1, float* __restrict__ T02,
                                              int Epad, int cstride, int nkc) {
  const int g = blockIdx.y, kc = blockIdx.x;
  const int col = threadIdx.x;
  const int* perm_g = perm + (size_t)g * Epad;
  const float* E1_g = E1 + (size_t)g * Epad;
  const float* E02_g = E02 + (size_t)g * Epad;
  float* C1_g = C1 + (size_t)g * cstride * CW;
  float* C02_g = C02 + (size_t)g * cstride * CW;
  const bool datacol = (col < DD);
  const float wden = (col == DD) ? 1.f : 0.f;
  float acc1 = 0.f, acc2 = 0.f;
  const int k0 = kc * 256;
#pragma unroll 8
  for (int kk = 0; kk < 256; ++kk) {
    int k = k0 + kk;
    int tok = perm_g[k];
    float e1 = E1_g[k], e02 = E02_g[k];
    float w = datacol ? base[(size_t)tok * DD + col] : wden;
    acc1 = fmaf(e1, w, acc1);
    acc2 = fmaf(e02, w, acc2);
    if ((kk & 15) == 15) {
      int t = (k + 1) >> 4;
      if (col < CW) { C1_g[(size_t)t * CW + col] = acc1; C02_g[(size_t)t * CW + col] = acc2; }
    }
  }
  if (col < CW) {
    T1[((size_t)g * nkc + kc) * CW + col] = acc1;
    T02[((size_t)g * nkc + kc) * CW + col] = acc2;
  }
}

// ---------------------------------------------------------------------------
// Bucketed GAT row construction with inline prefix fix-up.
// Phase 1: concurrent (unrolled+predicated) T-row loads, 16 prefetched
//          residual EW rows, level build in LDS.
// Phase 2: wave-aligned rows (wave w -> rows i0+w, i0+w+5, ...), float4 LDS
//          reads (conflict-free ds_read_b128), 8-B bf16x4 stores.
// ---------------------------------------------------------------------------
__global__ __launch_bounds__(320) void k_rows2(
    const float* __restrict__ base,
    const int* __restrict__ perm, const float* __restrict__ E1, const float* __restrict__ E02,
    const float* __restrict__ C1, const float* __restrict__ C02,
    const float* __restrict__ T1, const float* __restrict__ T02,
    const int* __restrict__ rlist, const float* __restrict__ rs1,
    const int* __restrict__ boff,
    __hip_bfloat16* __restrict__ gout,
    int N, int NT, int Epad, int NB, int nkc) {
  __shared__ float U1[16][CW];
  __shared__ float U02[16][CW];
  __shared__ int tokL[16];
  __shared__ float e1L[16], e02L[16];
  const int t = blockIdx.x, g = blockIdx.y;
  const int col = threadIdx.x;
  const int* boff_g = boff + (size_t)g * (NB + 2);
  const int i0 = boff_g[t], i1 = boff_g[t + 1];
  if (i0 >= i1) return;
  const int* perm_g = perm + (size_t)g * Epad;
  const float* E1_g = E1 + (size_t)g * Epad;
  const float* E02_g = E02 + (size_t)g * Epad;
  if (col < 16) {
    int idx = t * 16 + col;
    bool v = idx < N;
    tokL[col] = v ? perm_g[idx] : 0;
    e1L[col] = v ? E1_g[idx] : 0.f;
    e02L[col] = v ? E02_g[idx] : 0.f;
  }
  __syncthreads();
  if (col < CW) {
    const int kc = (t == 0) ? 0 : ((t - 1) >> 4);
    float tot1 = 0.f, pre1 = 0.f, pre02 = 0.f;
#pragma unroll
    for (int c = 0; c < 13; ++c) {          // max nkc; predicated -> concurrent loads
      if (c < nkc) {
        float tv = T1[((size_t)g * nkc + c) * CW + col];
        tot1 += tv;
        if (c < kc) {
          pre1 += tv;
          pre02 += T02[((size_t)g * nkc + c) * CW + col];
        }
      }
    }
    if (t > 0) {
      pre1 += C1[((size_t)g * (NT + 1) + t) * CW + col];
      pre02 += C02[((size_t)g * (NT + 1) + t) * CW + col];
    }
    float u1 = tot1 - pre1;
    float u02 = pre02;
    float wv[16];
#pragma unroll
    for (int j = 0; j < 16; ++j) {
      if (col < DD) wv[j] = ((t * 16 + j) < N) ? base[(size_t)tokL[j] * DD + col] : 0.f;
      else wv[j] = (col == DD) ? 1.f : 0.f;
    }
#pragma unroll
    for (int j = 0; j < 16; ++j) {
      U1[j][col] = u1; U02[j][col] = u02;
      u1 = fmaf(-e1L[j], wv[j], u1);
      u02 = fmaf(e02L[j], wv[j], u02);
    }
  }
  __syncthreads();
  const int wave = col >> 6, lane = col & 63;
  const int* rlist_g = rlist + (size_t)g * N;
  const float* rs1_g = rs1 + (size_t)g * N;
  for (int i = i0 + wave; i < i1; i += 5) {
    int e = rlist_g[i];
    int r = e & 0xffff, nr = (e >> 16) & 15;
    float s1 = rs1_g[i];
    float es1 = expf(s1), es02 = expf(0.2f * s1);
    float den = es1 * U1[nr][DD] + es02 * U02[nr][DD];
    float rden = 1.f / den;
    __hip_bfloat16* gr = gout + ((size_t)g * N + r) * GSTR;
#pragma unroll
    for (int cc = 0; cc < 2; ++cc) {
      int ch = lane + 64 * cc;               // 16-B column chunk index
      if (ch < 80) {
        short ov[4];
        if (ch < 75) {                        // cols 0..299
          const int c0 = ch * 4;
          float4 u1v = *(const float4*)&U1[nr][c0];
          float4 u2v = *(const float4*)&U02[nr][c0];
          float n0 = fmaf(es1, u1v.x, es02 * u2v.x) * rden;
          float n1 = fmaf(es1, u1v.y, es02 * u2v.y) * rden;
          float n2 = fmaf(es1, u1v.z, es02 * u2v.z) * rden;
          float n3 = fmaf(es1, u1v.w, es02 * u2v.w) * rden;
          float g0 = (n0 > 0.f) ? n0 : expm1f(n0);
          float g1 = (n1 > 0.f) ? n1 : expm1f(n1);
          float g2 = (n2 > 0.f) ? n2 : expm1f(n2);
          float g3 = (n3 > 0.f) ? n3 : expm1f(n3);
          __hip_bfloat16 h0 = __float2bfloat16(g0), h1 = __float2bfloat16(g1);
          __hip_bfloat16 h2 = __float2bfloat16(g2), h3 = __float2bfloat16(g3);
          ov[0] = *(short*)&h0; ov[1] = *(short*)&h1;
          ov[2] = *(short*)&h2; ov[3] = *(short*)&h3;
        } else {                              // cols 300..319 zero pad
          ov[0] = ov[1] = ov[2] = ov[3] = 0;
        }
        *(bf16x4*)(gr + ch * 4) = *(bf16x4*)ov;
      }
    }
  }
}

// ---------------------------------------------------------------------------
// Fused news logits + additive attention, LDS-STAGED B (canonical GEMM form).
// Block = 512 threads (8 waves) = 128 rows = 4 (b,m) groups.
// ---------------------------------------------------------------------------
__global__ __launch_bounds__(512) void k_logits_attn(
    const __hip_bfloat16* __restrict__ g, const __hip_bfloat16* __restrict__ Bp,
    const float* __restrict__ lin_b, const float* __restrict__ query,
    float* __restrict__ cand_enc, float* __restrict__ clicked_enc) {
  __shared__ __align__(16) short Bs[2][NTILES_N * 512];  // 2 x 13312 B
  __shared__ float lg[128];
  __shared__ float wgt[128];
  __shared__ float accw[8][GSTR];
  const int tid = threadIdx.x;
  const int wave = tid >> 6, lane = tid & 63;
  const int quad = lane >> 4, l16 = lane & 15;
  const int m = blockIdx.x >> 4;             // 16 blocks per gat
  const int rbase = (blockIdx.x & 15) * 128; // row within gat
  const __hip_bfloat16* grow =
      g + ((size_t)m * NROW + rbase + wave * 16 + l16) * GSTR + quad * 8;
  bf16x8 afr[KTILES];
#pragma unroll
  for (int kt = 0; kt < KTILES; ++kt) afr[kt] = *(const bf16x8*)(grow + kt * 32);

  const float4* bsrc = (const float4*)Bp;
  float4* bdst0 = (float4*)&Bs[0][0];
  float4* bdst1 = (float4*)&Bs[1][0];
  float4 st0, st1;
  {
    st0 = bsrc[tid];
    if (tid < KTCHUNK - 512) st1 = bsrc[512 + tid];
    bdst0[tid] = st0;
    if (tid < KTCHUNK - 512) bdst0[512 + tid] = st1;
    st0 = bsrc[KTCHUNK + tid];
    if (tid < KTCHUNK - 512) st1 = bsrc[KTCHUNK + 512 + tid];
  }
  __syncthreads();
  f32x4 acc[NTILES_N];
#pragma unroll
  for (int nt = 0; nt < NTILES_N; ++nt) acc[nt] = (f32x4){0.f, 0.f, 0.f, 0.f};
  int c = 0;
  for (int kt = 0; kt < KTILES; ++kt) {
    const bf16x8* bp = (const bf16x8*)&Bs[c][0] + lane;
#pragma unroll
    for (int nt = 0; nt < NTILES_N; ++nt)
      acc[nt] = __builtin_amdgcn_mfma_f32_16x16x32_bf16(afr[kt], bp[nt * 64], acc[nt], 0, 0, 0);
    if (kt < KTILES - 1) {
      __syncthreads();
      float4* bd = c ? bdst0 : bdst1;
      bd[tid] = st0;
      if (tid < KTCHUNK - 512) bd[512 + tid] = st1;
      if (kt < KTILES - 2) {
        st0 = bsrc[(size_t)(kt + 2) * KTCHUNK + tid];
        if (tid < KTCHUNK - 512) st1 = bsrc[(size_t)(kt + 2) * KTCHUNK + 512 + tid];
      }
      __syncthreads();
      c ^= 1;
    }
  }
  float part[4] = {0.f, 0.f, 0.f, 0.f};
#pragma unroll
  for (int nt = 0; nt < NTILES_N; ++nt) {
    const int n = nt * 16 + l16;
    const float qv = (n < QQ) ? query[n] : 0.f;
    const float bv = (n < QQ) ? lin_b[n] : 0.f;
#pragma unroll
    for (int r = 0; r < 4; ++r)
      part[r] = fmaf(tanhf(acc[nt][r] + bv), qv, part[r]);
  }
#pragma unroll
  for (int r = 0; r < 4; ++r) {
    float p = part[r];
    p += __shfl_xor(p, 1, 64); p += __shfl_xor(p, 2, 64);
    p += __shfl_xor(p, 4, 64); p += __shfl_xor(p, 8, 64);
    if (l16 == 0) lg[wave * 16 + quad * 4 + r] = p;
  }
  __syncthreads();
  if (tid < 128) {
    float v = lg[tid];
    float mx = v;
    mx = fmaxf(mx, __shfl_xor(mx, 1, 64)); mx = fmaxf(mx, __shfl_xor(mx, 2, 64));
    mx = fmaxf(mx, __shfl_xor(mx, 4, 64)); mx = fmaxf(mx, __shfl_xor(mx, 8, 64));
    mx = fmaxf(mx, __shfl_xor(mx, 16, 64));
    float e = expf(v - mx), sm = e;
    sm += __shfl_xor(sm, 1, 64); sm += __shfl_xor(sm, 2, 64);
    sm += __shfl_xor(sm, 4, 64); sm += __shfl_xor(sm, 8, 64);
    sm += __shfl_xor(sm, 16, 64);
    wgt[tid] = e / sm;
  }
  __syncthreads();
  const float w = wgt[wave * 16 + l16];
#pragma unroll
  for (int kt = 0; kt < KTILES; ++kt) {
#pragma unroll
    for (int j = 0; j < 8; ++j) {
      float v = bf2f(afr[kt][j]) * w;
      v += __shfl_xor(v, 1, 64); v += __shfl_xor(v, 2, 64);
      v += __shfl_xor(v, 4, 64); v += __shfl_xor(v, 8, 64);
      if (l16 == 0) accw[wave][kt * 32 + quad * 8 + j] = v;
    }
  }
  __syncthreads();
  const int b0 = rbase >> 5;
  for (int idx = tid; idx < 4 * DD; idx += 512) {
    int j = idx / DD, cc = idx % DD;
    float* op = (m < NC) ? (cand_enc + ((size_t)(b0 + j) * NC + m) * DD)
                         : (clicked_enc + ((size_t)(b0 + j) * NH + (m - NC)) * DD);
    op[cc] = accw[2 * j][cc] + accw[2 * j + 1][cc];
  }
}

// ---------------------------------------------------------------------------
// Fused user logits + attention + click-score dot. Block = one b (50 rows).
// ---------------------------------------------------------------------------
__global__ __launch_bounds__(256) void k_user_attn(
    const __hip_bfloat16* __restrict__ g, const __hip_bfloat16* __restrict__ Bp,
    const float* __restrict__ lin_b, const float* __restrict__ query,
    const float* __restrict__ cand_enc, float* __restrict__ out) {
  __shared__ float lg[64];
  __shared__ float wgt[64];
  __shared__ float accw[4][GSTR];
  __shared__ float uenc[CW];
  __shared__ float wred[4];
  const int b = blockIdx.x, tid = threadIdx.x;
  const int wave = tid >> 6, lane = tid & 63;
  const int quad = lane >> 4, l16 = lane & 15;
  const int rl = wave * 16 + l16;
  const int rclamp = (rl < NH) ? rl : 0;
  const __hip_bfloat16* grow = g + ((size_t)b * NH + rclamp) * GSTR + quad * 8;
  bf16x8 afr[KTILES];
#pragma unroll
  for (int kt = 0; kt < KTILES; ++kt) afr[kt] = *(const bf16x8*)(grow + kt * 32);
  f32x4 acc[NTILES_N];
#pragma unroll
  for (int nt = 0; nt < NTILES_N; ++nt) acc[nt] = (f32x4){0.f, 0.f, 0.f, 0.f};
  for (int kt = 0; kt < KTILES; ++kt) {
    const bf16x8* bp = (const bf16x8*)Bp + (size_t)kt * NTILES_N * 64 + lane;
#pragma unroll
    for (int nt = 0; nt < NTILES_N; ++nt)
      acc[nt] = __builtin_amdgcn_mfma_f32_16x16x32_bf16(afr[kt], bp[nt * 64], acc[nt], 0, 0, 0);
  }
  float part[4] = {0.f, 0.f, 0.f, 0.f};
#pragma unroll
  for (int nt = 0; nt < NTILES_N; ++nt) {
    const int n = nt * 16 + l16;
    const float qv = (n < QQ) ? query[n] : 0.f;
    const float bv = (n < QQ) ? lin_b[n] : 0.f;
#pragma unroll
    for (int r = 0; r < 4; ++r)
      part[r] = fmaf(tanhf(acc[nt][r] + bv), qv, part[r]);
  }
#pragma unroll
  for (int r = 0; r < 4; ++r) {
    float p = part[r];
    p += __shfl_xor(p, 1, 64); p += __shfl_xor(p, 2, 64);
    p += __shfl_xor(p, 4, 64); p += __shfl_xor(p, 8, 64);
    if (l16 == 0) lg[wave * 16 + quad * 4 + r] = p;
  }
  __syncthreads();
  if (tid < 64) {
    float v = (tid < NH) ? lg[tid] : -3.4e38f;
    float mx = v;
    for (int o = 32; o; o >>= 1) mx = fmaxf(mx, __shfl_xor(mx, o, 64));
    float e = (tid < NH) ? expf(v - mx) : 0.f;
    float sm = e;
    for (int o = 32; o; o >>= 1) sm += __shfl_xor(sm, o, 64);
    wgt[tid] = (tid < NH) ? e / sm : 0.f;
  }
  __syncthreads();
  const float w = (rl < NH) ? wgt[rl] : 0.f;
#pragma unroll
  for (int kt = 0; kt < KTILES; ++kt) {
#pragma unroll
    for (int j = 0; j < 8; ++j) {
      float v = bf2f(afr[kt][j]) * w;
      v += __shfl_xor(v, 1, 64); v += __shfl_xor(v, 2, 64);
      v += __shfl_xor(v, 4, 64); v += __shfl_xor(v, 8, 64);
      if (l16 == 0) accw[wave][kt * 32 + quad * 8 + j] = v;
    }
  }
  __syncthreads();
  for (int c = tid; c < DD; c += 256)
    uenc[c] = accw[0][c] + accw[1][c] + accw[2][c] + accw[3][c];
  __syncthreads();
  for (int c5 = 0; c5 < NC; ++c5) {
    const float* cp = cand_enc + ((size_t)b * NC + c5) * DD;
    float s = 0.f;
    for (int d = tid; d < DD; d += 256) s = fmaf(uenc[d], cp[d], s);
    for (int o = 32; o; o >>= 1) s += __shfl_xor(s, o, 64);
    if (lane == 0) wred[wave] = s;
    __syncthreads();
    if (tid == 0) out[b * NC + c5] = wred[0] + wred[1] + wred[2] + wred[3];
    __syncthreads();
  }
}

// ---------------------------------------------------------------------------
extern "C" void kernel_launch(void* const* d_in, const int* in_sizes, int n_in,
                              void* d_out, int out_size, void* d_ws, size_t ws_size,
                              hipStream_t stream) {
  const int* cand = (const int*)d_in[0];
  const int* clicked = (const int*)d_in[1];
  const float* emb = (const float*)d_in[2];
  const float* news_W = (const float*)d_in[3];
  const float* news_a = (const float*)d_in[4];
  const float* news_lw = (const float*)d_in[5];
  const float* news_lb = (const float*)d_in[6];
  const float* news_q = (const float*)d_in[7];
  const float* user_W = (const float*)d_in[8];
  const float* user_a = (const float*)d_in[9];
  const float* user_lw = (const float*)d_in[10];
  const float* user_lb = (const float*)d_in[11];
  const float* user_q = (const float*)d_in[12];
  float* out = (float*)d_out;

  float* W = (float*)d_ws;
  size_t o = 0;
  auto nxt = [&](size_t n) { size_t c = o; o += (n + 63) & ~(size_t)63; return c; };
  float* EW = W + nxt((size_t)NVOC * DD);
  float* s1v = W + nxt(NVOC);
  float* s2v = W + nxt(NVOC);
  int* perm = (int*)(W + nxt((size_t)NGAT * NROW));
  float* E1 = W + nxt((size_t)NGAT * NROW);
  float* E02 = W + nxt((size_t)NGAT * NROW);
  float* C1 = W + nxt((size_t)NGAT * (NT_NEWS + 1) * CW);
  float* C02 = W + nxt((size_t)NGAT * (NT_NEWS + 1) * CW);
  float* T1N = W + nxt((size_t)NGAT * 8 * CW);
  float* T02N = W + nxt((size_t)NGAT * 8 * CW);
  int* rlistN = (int*)(W + nxt((size_t)NGAT * NROW));
  float* rs1N = W + nxt((size_t)NGAT * NROW);
  int* boffN = (int*)(W + nxt((size_t)NGAT * (NB_NEWS + 2)));
  float* cand_enc = W + nxt((size_t)BN_B * NC * DD);
  float* clicked_enc = W + nxt((size_t)BN_B * NH * DD);
  float* WhU = W + nxt((size_t)NUSR * DD);
  float* s1u = W + nxt(NUSR);
  float* s2u = W + nxt(NUSR);
  int* permU = (int*)(W + nxt(NUSR_PAD));
  float* E1U = W + nxt(NUSR_PAD);
  float* E02U = W + nxt(NUSR_PAD);
  float* C1U = W + nxt((size_t)(NT_USER + 1) * CW);
  float* C02U = W + nxt((size_t)(NT_USER + 1) * CW);
  float* T1U = W + nxt((size_t)13 * CW);
  float* T02U = W + nxt((size_t)13 * CW);
  int* rlistU = (int*)(W + nxt(NUSR));
  float* rs1U = W + nxt(NUSR);
  int* boffU = (int*)(W + nxt(NB_USER + 2));
  __hip_bfloat16* BpN = (__hip_bfloat16*)(W + nxt((size_t)BPELT * 8 / 2));
  __hip_bfloat16* BpU = (__hip_bfloat16*)(W + nxt((size_t)BPELT * 8 / 2));
  __hip_bfloat16* WhiN = (__hip_bfloat16*)(W + nxt((size_t)WPELT * 8 / 2));
  __hip_bfloat16* WloN = (__hip_bfloat16*)(W + nxt((size_t)WPELT * 8 / 2));
  __hip_bfloat16* WhiU = (__hip_bfloat16*)(W + nxt((size_t)WPELT * 8 / 2));
  __hip_bfloat16* WloU = (__hip_bfloat16*)(W + nxt((size_t)WPELT * 8 / 2));
  __hip_bfloat16* g_news = (__hip_bfloat16*)(W + nxt((size_t)NGAT * NROW * GSTR / 2));
  __hip_bfloat16* g_user = (__hip_bfloat16*)(W + nxt((size_t)NUSR * GSTR / 2));

  const int packgrid = (BPELT + 255) / 256;
  const int packWgrid = (WPELT + 255) / 256;

  // 1. packs (news+user in one launch each)
  k_packW<<<dim3(packWgrid, 2), 256, 0, stream>>>(news_W, user_W, WhiN, WloN, WhiU, WloU);
  k_packB<<<dim3(packgrid, 2), 256, 0, stream>>>(news_lw, user_lw, BpN, BpU);
  // 2. EW = emb @ news_W  (+ fused s1/s2)
  k_gemm_mfma<<<(NVOC + 63) / 64, 256, 0, stream>>>(emb, WhiN, WloN, news_a, EW, s1v, s2v, NVOC);
  // 3. sort + exp tables + rank/bucket per news GAT
  k_sort2<<<NGAT, 1024, 0, stream>>>(cand, clicked, s2v, s1v, perm, E1, E02,
                                     rlistN, rs1N, boffN, 0, NROW, NROW, NROW, NB_NEWS);
  // 4. coarse weighted prefix sums (local) + totals
  k_scan<<<dim3(8, NGAT), 320, 0, stream>>>(EW, perm, E1, E02, C1, C02, T1N, T02N,
                                            NROW, NT_NEWS + 1, 8);
  // 5. bucketed GAT rows (inline fix-up) -> g_news
  k_rows2<<<dim3(NB_NEWS + 1, NGAT), 320, 0, stream>>>(EW, perm, E1, E02, C1, C02, T1N, T02N,
                                                       rlistN, rs1N, boffN, g_news,
                                                       NROW, NT_NEWS, NROW, NB_NEWS, 8);
  // 6. fused logits+attention (LDS-staged GEMM) -> cand/clicked encodings
  k_logits_attn<<<NGAT * NROW / 128, 512, 0, stream>>>(g_news, BpN, news_lb, news_q,
                                                       cand_enc, clicked_enc);
  // 7-10. user GAT
  k_gemm_mfma<<<(NUSR + 63) / 64, 256, 0, stream>>>(clicked_enc, WhiU, WloU, user_a,
                                                    WhU, s1u, s2u, NUSR);
  k_sort2<<<1, 1024, 0, stream>>>(nullptr, nullptr, s2u, s1u, permU, E1U, E02U,
                                  rlistU, rs1U, boffU, 1, NUSR, 4096, NUSR_PAD, NB_USER);
  k_scan<<<dim3(13, 1), 320, 0, stream>>>(WhU, permU, E1U, E02U, C1U, C02U, T1U, T02U,
                                          NUSR_PAD, NT_USER + 1, 13);
  k_rows2<<<dim3(NB_USER + 1, 1), 320, 0, stream>>>(WhU, permU, E1U, E02U, C1U, C02U, T1U, T02U,
                                                    rlistU, rs1U, boffU, g_user,
                                                    NUSR, NT_USER, NUSR_PAD, NB_USER, 13);
  // 11. fused user logits + attention + click score
  k_user_attn<<<BN_B, 256, 0, stream>>>(g_user, BpU, user_lb, user_q, cand_enc, out);
}